// Round 9
// baseline (396.196 us; speedup 1.0000x reference)
//
#include <hip/hip_runtime.h>
#include <hip/hip_bf16.h>
#include <math.h>

// Problem constants
constexpr int T_ = 512;
constexpr int B_ = 4;
constexpr int E_ = 1024;
constexpr int H_ = 16;
constexpr int NGRAM_ = 2;
constexpr int TGT_ = (1 + NGRAM_) * T_;   // 1536
constexpr int ROWS_ = TGT_ * B_;          // 6144

typedef __bf16 bf16_t;
typedef __bf16 bf16x8 __attribute__((ext_vector_type(8)));
typedef __bf16 bf16x4 __attribute__((ext_vector_type(4)));
typedef float f32x4 __attribute__((ext_vector_type(4)));

#define GLL(gaddr, laddr)                                                     \
  __builtin_amdgcn_global_load_lds(                                           \
      (const __attribute__((address_space(1))) void*)(gaddr),                 \
      (__attribute__((address_space(3))) void*)(laddr), 16, 0, 0)

// raw barrier / counted waits: asm with memory clobber = compiler fence,
// no compiler-inserted vmcnt(0) drain (unlike __syncthreads()).
#define BARX()   asm volatile("s_barrier" ::: "memory")
#define WVM7()   asm volatile("s_waitcnt vmcnt(7)" ::: "memory")
#define WVM10()  asm volatile("s_waitcnt vmcnt(10)" ::: "memory")
#define WVM0()   asm volatile("s_waitcnt vmcnt(0)" ::: "memory")

constexpr float LOG2E_ = 1.44269504088896f;
#define EXP2F(x) __builtin_amdgcn_exp2f(x)

// ---------------------------------------------------------------------------
// prep: all fp32->bf16 conversions, one launch.
// ---------------------------------------------------------------------------
__global__ __launch_bounds__(256) void prep(
    const float* __restrict__ query, const float* __restrict__ ipw,
    const float* __restrict__ relw, const float* __restrict__ outw,
    bf16_t* __restrict__ qb, bf16_t* __restrict__ ipwb,
    bf16_t* __restrict__ relwb, bf16_t* __restrict__ outwb) {
  const int i = blockIdx.x * 256 + threadIdx.x;
  constexpr int N1 = ROWS_ * E_ / 4;
  constexpr int N2 = 3 * E_ * E_ / 4;
  constexpr int N3 = 512 * E_ / 4;
  constexpr int N4 = E_ * E_ / 4;
  const float4* src;
  bf16_t* dst;
  int j = i;
  if (i < N1) { src = (const float4*)query; dst = qb; }
  else if (i < N1 + N2) { src = (const float4*)ipw; dst = ipwb; j = i - N1; }
  else if (i < N1 + N2 + N3) { src = (const float4*)relw; dst = relwb; j = i - N1 - N2; }
  else if (i < N1 + N2 + N3 + N4) { src = (const float4*)outw; dst = outwb; j = i - N1 - N2 - N3; }
  else return;
  const float4 v = src[j];
  bf16x4 o;
  o[0] = (bf16_t)v.x; o[1] = (bf16_t)v.y;
  o[2] = (bf16_t)v.z; o[3] = (bf16_t)v.w;
  ((bf16x4*)dst)[j] = o;
}

// ---------------------------------------------------------------------------
// Combined projection GEMM, BM=192 x BN=256 x BK=64, 512 threads, r2
// schedule, split in two dispatches. Q is scaled by 0.125*log2(e) so the
// attention softmax can use exp2 directly (exp(x) == exp2(x*log2e)).
// ---------------------------------------------------------------------------
__device__ __forceinline__ int sw256(int row, int col) {
  // XOR-swizzled bounce layout for the 192x256 V-tile transpose
  return row * 256 + ((((col >> 3) ^ (row & 31)) << 3) | (col & 7));
}

__global__ __launch_bounds__(512, 2) void bgemm_proj(
    const bf16_t* __restrict__ A, const bf16_t* __restrict__ W,
    const float* __restrict__ ipb, const float* __restrict__ relb,
    bf16_t* __restrict__ qkvb, float* __restrict__ relv2,
    bf16_t* __restrict__ vT, int bn0) {
  // [As0|As1] 2x192x64, [Bs0|Bs1] 2x256x64  (112 KB total)
  __shared__ bf16_t smem[57344];
  bf16_t* As0 = smem;
  bf16_t* As1 = smem + 12288;
  bf16_t* Bs0 = smem + 24576;
  bf16_t* Bs1 = smem + 24576 + 16384;

  const int tid = threadIdx.x;
  const int wave = tid >> 6, lane = tid & 63;
  const int wr = wave >> 2, wc = wave & 3;       // 2 x 4 wave grid
  // bijective XCD swizzle; nwg is 256 or 192, both divisible by 8.
  const int nx = gridDim.x;
  const int pid = blockIdx.y * nx + blockIdx.x;
  const int chunk = (nx * gridDim.y) >> 3;
  const int lid = (pid & 7) * chunk + (pid >> 3);
  const int by = lid / nx;
  const int bx = lid - by * nx;
  const int bm = by * 192, bn = bn0 + bx * 256;
  const int q = lane >> 4, ln = lane & 15;
  const int grow = tid >> 3;                              // 0..63
  const int gcol = ((tid & 7) ^ (grow & 7)) * 8;          // pre-swizzled src
  const int co[2] = {((q) ^ (ln & 7)) * 8, ((4 + q) ^ (ln & 7)) * 8};

  f32x4 acc[6][4];
#pragma unroll
  for (int mi = 0; mi < 6; ++mi)
#pragma unroll
    for (int ni = 0; ni < 4; ++ni)
#pragma unroll
      for (int r = 0; r < 4; ++r) acc[mi][ni][r] = 0.f;

  // stage one K-tile (7 GLL per thread: 3 A-rounds + 4 B-rounds of 64 rows)
  auto stage = [&](int kt, bf16_t* la, bf16_t* lb) {
    const int kc = kt * 64 + gcol;
#pragma unroll
    for (int p = 0; p < 3; ++p)
      GLL(&A[(size_t)(bm + p * 64 + grow) * 1024 + kc], &la[p * 4096 + tid * 8]);
#pragma unroll
    for (int p = 0; p < 4; ++p)
      GLL(&W[(size_t)(bn + p * 64 + grow) * 1024 + kc], &lb[p * 4096 + tid * 8]);
  };

  // One K-tile, barrier-free inside: reads prefetched 1 sub-phase deep.
  auto compute_tile = [&](const bf16_t* la, const bf16_t* lb) {
    bf16x8 a0[3], a1[3], b0[4], b1[4];
#pragma unroll
    for (int ni = 0; ni < 4; ++ni)
      b0[ni] = *(const bf16x8*)&lb[(wc * 64 + ni * 16 + ln) * 64 + co[0]];
#pragma unroll
    for (int mi = 0; mi < 3; ++mi)
      a0[mi] = *(const bf16x8*)&la[(wr * 96 + mi * 16 + ln) * 64 + co[0]];
#pragma unroll
    for (int mi = 0; mi < 3; ++mi)
      a1[mi] = *(const bf16x8*)&la[(wr * 96 + (3 + mi) * 16 + ln) * 64 + co[0]];
    __builtin_amdgcn_s_setprio(1);
#pragma unroll
    for (int mi = 0; mi < 3; ++mi)
#pragma unroll
      for (int ni = 0; ni < 4; ++ni)
        acc[mi][ni] = __builtin_amdgcn_mfma_f32_16x16x32_bf16(
            a0[mi], b0[ni], acc[mi][ni], 0, 0, 0);
    __builtin_amdgcn_s_setprio(0);
#pragma unroll
    for (int ni = 0; ni < 4; ++ni)
      b1[ni] = *(const bf16x8*)&lb[(wc * 64 + ni * 16 + ln) * 64 + co[1]];
#pragma unroll
    for (int mi = 0; mi < 3; ++mi)
      a0[mi] = *(const bf16x8*)&la[(wr * 96 + mi * 16 + ln) * 64 + co[1]];
    __builtin_amdgcn_s_setprio(1);
#pragma unroll
    for (int mi = 0; mi < 3; ++mi)
#pragma unroll
      for (int ni = 0; ni < 4; ++ni)
        acc[3 + mi][ni] = __builtin_amdgcn_mfma_f32_16x16x32_bf16(
            a1[mi], b0[ni], acc[3 + mi][ni], 0, 0, 0);
    __builtin_amdgcn_s_setprio(0);
#pragma unroll
    for (int mi = 0; mi < 3; ++mi)
      a1[mi] = *(const bf16x8*)&la[(wr * 96 + (3 + mi) * 16 + ln) * 64 + co[1]];
    __builtin_amdgcn_s_setprio(1);
#pragma unroll
    for (int mi = 0; mi < 3; ++mi)
#pragma unroll
      for (int ni = 0; ni < 4; ++ni)
        acc[mi][ni] = __builtin_amdgcn_mfma_f32_16x16x32_bf16(
            a0[mi], b1[ni], acc[mi][ni], 0, 0, 0);
    __builtin_amdgcn_s_setprio(0);
    __builtin_amdgcn_s_setprio(1);
#pragma unroll
    for (int mi = 0; mi < 3; ++mi)
#pragma unroll
      for (int ni = 0; ni < 4; ++ni)
        acc[3 + mi][ni] = __builtin_amdgcn_mfma_f32_16x16x32_bf16(
            a1[mi], b1[ni], acc[3 + mi][ni], 0, 0, 0);
    __builtin_amdgcn_s_setprio(0);
  };

  // prologue: 2 K-tiles in flight (14 outstanding GLL per thread)
  stage(0, As0, Bs0);
  stage(1, As1, Bs1);

  for (int kt = 0; kt < 16; kt += 2) {
    WVM7(); BARX();                       // tile kt resident for all waves
    compute_tile(As0, Bs0);
    BARX();                               // all waves done reading buf0
    if (kt + 2 < 16) stage(kt + 2, As0, Bs0);
    if (kt < 14) { WVM7(); } else { WVM0(); }   // tile kt+1 resident
    BARX();
    compute_tile(As1, Bs1);
    BARX();                               // all waves done reading buf1
    if (kt + 3 < 16) stage(kt + 3, As1, Bs1);
  }

  // ---------------- epilogue (per-block uniform routing) -------------------
  if (bn < 2048) {
    // Q (scaled by 0.125*log2e for exp2 softmax) and K -> qkvb
    const float sc = (bn < 1024) ? 0.125f * LOG2E_ : 1.0f;
#pragma unroll
    for (int mi = 0; mi < 6; ++mi) {
#pragma unroll
      for (int ni = 0; ni < 4; ++ni) {
        const int col = bn + wc * 64 + ni * 16 + ln;
        const float bv = ipb[col];
#pragma unroll
        for (int r = 0; r < 4; ++r) {
          const int row = bm + wr * 96 + mi * 16 + q * 4 + r;
          qkvb[(size_t)row * 3072 + col] = (bf16_t)((acc[mi][ni][r] + bv) * sc);
        }
      }
    }
  } else if (bn < 3072) {
    // V: transpose in-block via swizzled LDS bounce, write vT[bh][d][token]
    __syncthreads();  // K-loop LDS fully drained; reuse smem as bounce
#pragma unroll
    for (int mi = 0; mi < 6; ++mi) {
#pragma unroll
      for (int ni = 0; ni < 4; ++ni) {
        const int col_l = wc * 64 + ni * 16 + ln;
        const float bv = ipb[bn + col_l];
#pragma unroll
        for (int r = 0; r < 4; ++r) {
          const int row_l = wr * 96 + mi * 16 + q * 4 + r;
          smem[sw256(row_l, col_l)] = (bf16_t)(acc[mi][ni][r] + bv);
        }
      }
    }
    __syncthreads();
    const int h0 = (bn - 2048) >> 6;     // 4 heads per 256-col tile
    const int tb0 = bm >> 2;             // 48 tokens per 192-row tile
#pragma unroll
    for (int e = 0; e < 2; ++e) {
      const int task = e * 512 + tid;    // 1024 tasks: (b, col)
      const int b = task & 3;
      const int c = task >> 2;           // 0..255
      const int h = h0 + (c >> 6);
      const int d = c & 63;
      const size_t base = ((size_t)((b * 16 + h) * 64 + d)) * (size_t)TGT_ + tb0;
#pragma unroll
      for (int k = 0; k < 6; ++k) {
        bf16x8 v8;
#pragma unroll
        for (int i = 0; i < 8; ++i)
          v8[i] = smem[sw256((k * 8 + i) * 4 + b, c)];
        *(bf16x8*)&vT[base + k * 8] = v8;
      }
    }
  } else {
    const int cb = bn - 3072 + wc * 64;
    float4 rb4;
#pragma unroll
    for (int ni = 0; ni < 4; ++ni)
      ((float*)&rb4)[ni] = relb[cb + ni * 16 + ln];
    const int bkbase = cb >> 4;
#pragma unroll
    for (int mi = 0; mi < 6; ++mi) {
#pragma unroll
      for (int r = 0; r < 4; ++r) {
        const int row = bm + wr * 96 + mi * 16 + q * 4 + r;
        float4 v;
        v.x = acc[mi][0][r] + rb4.x;
        v.y = acc[mi][1][r] + rb4.y;
        v.z = acc[mi][2][r] + rb4.z;
        v.w = acc[mi][3][r] + rb4.w;
        *(float4*)&relv2[(size_t)row * 512 + ln * 32 + bkbase] = v;
      }
    }
  }
}

// ---------------------------------------------------------------------------
// Output projection GEMM (fp32 out). BM=192 x BN=128, 256 threads, dbuf
// 80 KB LDS, grid 8x32 = 256 blocks = exactly 1 block/CU, single round.
// ---------------------------------------------------------------------------
__global__ __launch_bounds__(256, 1) void bgemm_out(
    const bf16_t* __restrict__ A, const bf16_t* __restrict__ W,
    const float* __restrict__ bias, float* __restrict__ C) {
  // slot s: A at s*20480 (192x64), B at s*20480+12288 (128x64); 80 KB
  __shared__ bf16_t smem[40960];

  const int tid = threadIdx.x;
  const int wave = tid >> 6, lane = tid & 63;
  const int wr = wave >> 1, wc = wave & 1;        // 2x2 wave grid
  const int pid = blockIdx.y * 8 + blockIdx.x;    // 256 = 8*32
  const int lid = (pid & 7) * 32 + (pid >> 3);
  const int bm = (lid >> 3) * 192, bn = (lid & 7) * 128;
  const int q = lane >> 4, ln = lane & 15;
  const int grow = tid >> 3;                      // 0..31
  const int gcol = ((tid & 7) ^ (grow & 7)) * 8;
  const int co[2] = {((q) ^ (ln & 7)) * 8, ((4 + q) ^ (ln & 7)) * 8};

  f32x4 acc[6][4];
#pragma unroll
  for (int mi = 0; mi < 6; ++mi)
#pragma unroll
    for (int ni = 0; ni < 4; ++ni)
#pragma unroll
      for (int r = 0; r < 4; ++r) acc[mi][ni][r] = 0.f;

  // 10 GLL per thread per tile: A 6 rounds of 32 rows, B 4 rounds.
  auto stage = [&](int kt) {
    bf16_t* s = smem + (kt & 1) * 20480;
    const int kc = kt * 64 + gcol;
#pragma unroll
    for (int p = 0; p < 6; ++p)
      GLL(&A[(size_t)(bm + p * 32 + grow) * 1024 + kc], &s[p * 2048 + tid * 8]);
#pragma unroll
    for (int p = 0; p < 4; ++p)
      GLL(&W[(size_t)(bn + p * 32 + grow) * 1024 + kc],
          &s[12288 + p * 2048 + tid * 8]);
  };

  auto compute_tile = [&](int kt) {
    const bf16_t* la = smem + (kt & 1) * 20480;
    const bf16_t* lb = la + 12288;
    bf16x8 a0[3], a1[3], b0[4], b1[4];
#pragma unroll
    for (int ni = 0; ni < 4; ++ni)
      b0[ni] = *(const bf16x8*)&lb[(wc * 64 + ni * 16 + ln) * 64 + co[0]];
#pragma unroll
    for (int mi = 0; mi < 3; ++mi)
      a0[mi] = *(const bf16x8*)&la[(wr * 96 + mi * 16 + ln) * 64 + co[0]];
#pragma unroll
    for (int mi = 0; mi < 3; ++mi)
      a1[mi] = *(const bf16x8*)&la[(wr * 96 + (3 + mi) * 16 + ln) * 64 + co[0]];
    __builtin_amdgcn_s_setprio(1);
#pragma unroll
    for (int mi = 0; mi < 3; ++mi)
#pragma unroll
      for (int ni = 0; ni < 4; ++ni)
        acc[mi][ni] = __builtin_amdgcn_mfma_f32_16x16x32_bf16(
            a0[mi], b0[ni], acc[mi][ni], 0, 0, 0);
    __builtin_amdgcn_s_setprio(0);
#pragma unroll
    for (int ni = 0; ni < 4; ++ni)
      b1[ni] = *(const bf16x8*)&lb[(wc * 64 + ni * 16 + ln) * 64 + co[1]];
#pragma unroll
    for (int mi = 0; mi < 3; ++mi)
      a0[mi] = *(const bf16x8*)&la[(wr * 96 + mi * 16 + ln) * 64 + co[1]];
    __builtin_amdgcn_s_setprio(1);
#pragma unroll
    for (int mi = 0; mi < 3; ++mi)
#pragma unroll
      for (int ni = 0; ni < 4; ++ni)
        acc[3 + mi][ni] = __builtin_amdgcn_mfma_f32_16x16x32_bf16(
            a1[mi], b0[ni], acc[3 + mi][ni], 0, 0, 0);
    __builtin_amdgcn_s_setprio(0);
#pragma unroll
    for (int mi = 0; mi < 3; ++mi)
      a1[mi] = *(const bf16x8*)&la[(wr * 96 + (3 + mi) * 16 + ln) * 64 + co[1]];
    __builtin_amdgcn_s_setprio(1);
#pragma unroll
    for (int mi = 0; mi < 3; ++mi)
#pragma unroll
      for (int ni = 0; ni < 4; ++ni)
        acc[mi][ni] = __builtin_amdgcn_mfma_f32_16x16x32_bf16(
            a0[mi], b1[ni], acc[mi][ni], 0, 0, 0);
    __builtin_amdgcn_s_setprio(0);
    __builtin_amdgcn_s_setprio(1);
#pragma unroll
    for (int mi = 0; mi < 3; ++mi)
#pragma unroll
      for (int ni = 0; ni < 4; ++ni)
        acc[3 + mi][ni] = __builtin_amdgcn_mfma_f32_16x16x32_bf16(
            a1[mi], b1[ni], acc[3 + mi][ni], 0, 0, 0);
    __builtin_amdgcn_s_setprio(0);
  };

  stage(0);
  stage(1);

  for (int kt = 0; kt < 16; kt += 2) {
    WVM10(); BARX();                      // tile kt resident
    compute_tile(kt);
    BARX();
    if (kt + 2 < 16) stage(kt + 2);
    if (kt < 14) { WVM10(); } else { WVM0(); }  // tile kt+1 resident
    BARX();
    compute_tile(kt + 1);
    BARX();
    if (kt + 3 < 16) stage(kt + 3);
  }

#pragma unroll
  for (int mi = 0; mi < 6; ++mi) {
#pragma unroll
    for (int ni = 0; ni < 4; ++ni) {
      const int col = bn + wc * 64 + ni * 16 + ln;
      const float bv = bias[col];
#pragma unroll
      for (int r = 0; r < 4; ++r) {
        const int row = bm + wr * 96 + mi * 16 + q * 4 + r;
        C[(size_t)row * 1024 + col] = acc[mi][ni][r] + bv;
      }
    }
  }
}

// ---------------------------------------------------------------------------
// MFMA flash attention. ROUND-9 (= round-8 with exp2 builtin fixed):
// 1024 blocks x 128 threads (2 waves): grid (bh=64 fast, 16=(qt-pair,rh)).
// Each block owns 32 Q-rows; single-buffered K/V staging (LDS ~26.5 KB ->
// 3 waves/SIMD occupancy). Q-row split needs NO combine (no running max).
// exp->exp2: Q pre-scaled by log2e in proj; bias scaled by log2e at staging.
// ---------------------------------------------------------------------------
__device__ __forceinline__ int bucket_of(int n) {
  if (n < 16) return n;
  const float lf = __log2f((float)n);
  int b = (int)(16.0f + (lf - 4.0f) * 5.3333333f);
  return b > 31 ? 31 : b;
}

__global__ __launch_bounds__(128, 3) void flash_mfma(
    const bf16_t* __restrict__ qkvb, const bf16_t* __restrict__ vT,
    const float* __restrict__ relv2, bf16_t* __restrict__ attn) {
  __shared__ bf16_t Ks[64 * 64];        // K tile (also Q z0/z1 in prologue)
  __shared__ bf16_t Vts[64 * 64];       // V^T tile (also Q z2 in prologue)
  __shared__ bf16_t Ps[2][16 * 64];
  __shared__ bf16_t biasS[3][32 * 33];

  const int bh = blockIdx.x;            // fast dim: uniform per XCD
  const int yy = blockIdx.y;            // 0..15
  const int rh = yy & 1;                // Q-row half
  const int qy = yy >> 1;
  const int qt = (qy < 4) ? (7 - qy) : (qy - 4);   // complementary pairs
  const int tq0 = qt * 64;
  const int rg0 = tq0 + rh * 32;        // global first Q-row of this block
  const int b = bh >> 4, h = bh & 15;
  const int tid = threadIdx.x;
  const int wave = tid >> 6, lane = tid & 63;
  const int q = lane >> 4, ln = lane & 15;
  const int m0 = wave * 16;             // local row base (0 or 16) within 32
  const int grow = tid >> 3;            // 0..15
  const int gcol = ((tid & 7) ^ (grow & 7)) * 8;
  const int co[2] = {((q) ^ (ln & 7)) * 8, ((4 + q) ^ (ln & 7)) * 8};

  // stage bias rows for this block's 32 Q-rows, scaled by log2e (exp2 path)
#pragma unroll
  for (int z = 0; z < 3; ++z) {
#pragma unroll
    for (int u = 0; u < 2; ++u) {
      const int c = u * 128 + tid;      // 0..255
      const int row = c >> 3, j4 = (c & 7) * 4;
      const float4 v = *(const float4*)
          &relv2[((size_t)(z * T_ + rg0 + row) * B_ + b) * 512 + h * 32 + j4];
      biasS[z][row * 33 + j4 + 0] = (bf16_t)(v.x * LOG2E_);
      biasS[z][row * 33 + j4 + 1] = (bf16_t)(v.y * LOG2E_);
      biasS[z][row * 33 + j4 + 2] = (bf16_t)(v.z * LOG2E_);
      biasS[z][row * 33 + j4 + 3] = (bf16_t)(v.w * LOG2E_);
    }
  }

  // stage the three 32-row Q tiles (z0 -> Ks[0:32], z1 -> Ks[32:64], z2 -> Vts)
#pragma unroll
  for (int u = 0; u < 2; ++u) {
    const int sr = u * 16 + grow;
    GLL(&qkvb[((size_t)(0 * T_ + rg0 + sr) * B_ + b) * 3072 + h * 64 + gcol],
        &Ks[u * 1024 + tid * 8]);
    GLL(&qkvb[((size_t)(1 * T_ + rg0 + sr) * B_ + b) * 3072 + h * 64 + gcol],
        &Ks[2048 + u * 1024 + tid * 8]);
    GLL(&qkvb[((size_t)(2 * T_ + rg0 + sr) * B_ + b) * 3072 + h * 64 + gcol],
        &Vts[u * 1024 + tid * 8]);
  }
  __syncthreads();

  bf16x8 aq[3][2];
  aq[0][0] = *(const bf16x8*)&Ks[(m0 + ln) * 64 + co[0]];
  aq[0][1] = *(const bf16x8*)&Ks[(m0 + ln) * 64 + co[1]];
  aq[1][0] = *(const bf16x8*)&Ks[(32 + m0 + ln) * 64 + co[0]];
  aq[1][1] = *(const bf16x8*)&Ks[(32 + m0 + ln) * 64 + co[1]];
  aq[2][0] = *(const bf16x8*)&Vts[(m0 + ln) * 64 + co[0]];
  aq[2][1] = *(const bf16x8*)&Vts[(m0 + ln) * 64 + co[1]];

  float bv31[3][4], bv0[3][4];
#pragma unroll
  for (int z = 0; z < 3; ++z)
#pragma unroll
    for (int r = 0; r < 4; ++r) {
      const int rloc = m0 + q * 4 + r;
      bv31[z][r] = (float)biasS[z][rloc * 33 + 31];
      bv0[z][r] = (float)biasS[z][rloc * 33];
    }

  f32x4 Od[3][4];
  float lpart[3][4];
#pragma unroll
  for (int z = 0; z < 3; ++z)
#pragma unroll
    for (int r = 0; r < 4; ++r) {
      lpart[z][r] = 0.f;
#pragma unroll
      for (int tc = 0; tc < 4; ++tc) Od[z][tc][r] = 0.f;
    }

  const int ntiles = qt + 3;

  // single-buffered K/V staging: full 64-token tile (8 GLL per thread)
  auto stage_tile = [&](int jj) {
    const int krb = (jj <= qt) ? jj * 64 : ((jj - qt) * T_ + tq0);
#pragma unroll
    for (int u = 0; u < 4; ++u) {
      const int sr = u * 16 + grow;
      GLL(&qkvb[((size_t)(krb + sr) * B_ + b) * 3072 + 1024 + h * 64 + gcol],
          &Ks[u * 1024 + tid * 8]);
      GLL(&vT[((size_t)bh * 64 + sr) * (size_t)TGT_ + krb + gcol],
          &Vts[u * 1024 + tid * 8]);
    }
  };

  __syncthreads();          // aq reads complete before overwriting buffers
  stage_tile(0);

  for (int jj = 0; jj < ntiles; ++jj) {
    __syncthreads();        // vmcnt+lgkm drained + barrier: tile jj resident

    const int krb = (jj <= qt) ? jj * 64 : ((jj - qt) * T_ + tq0);

    bf16x8 kf[4][2], vf[4][2];
#pragma unroll
    for (int tc = 0; tc < 4; ++tc) {
      kf[tc][0] = *(const bf16x8*)&Ks[(tc * 16 + ln) * 64 + co[0]];
      kf[tc][1] = *(const bf16x8*)&Ks[(tc * 16 + ln) * 64 + co[1]];
      vf[tc][0] = *(const bf16x8*)&Vts[(tc * 16 + ln) * 64 + co[0]];
      vf[tc][1] = *(const bf16x8*)&Vts[(tc * 16 + ln) * 64 + co[1]];
    }

    if (jj <= qt) {
      const bool far = (jj <= qt - 3);
      // ---- hoisted QK^T for all three streams ----
      f32x4 sc[3][4];
#pragma unroll
      for (int z = 0; z < 3; ++z)
#pragma unroll
        for (int tc = 0; tc < 4; ++tc)
#pragma unroll
          for (int r = 0; r < 4; ++r) sc[z][tc][r] = 0.f;
#pragma unroll
      for (int z = 0; z < 3; ++z)
#pragma unroll
        for (int tc = 0; tc < 4; ++tc) {
          sc[z][tc] = __builtin_amdgcn_mfma_f32_16x16x32_bf16(
              aq[z][0], kf[tc][0], sc[z][tc], 0, 0, 0);
          sc[z][tc] = __builtin_amdgcn_mfma_f32_16x16x32_bf16(
              aq[z][1], kf[tc][1], sc[z][tc], 0, 0, 0);
        }

      // ---- per stream: softmax (exp2) -> Ps -> PV ----
#pragma unroll
      for (int z = 0; z < 3; ++z) {
        if (far) {
#pragma unroll
          for (int r = 0; r < 4; ++r) {
            const float bv = bv31[z][r];
#pragma unroll
            for (int tc = 0; tc < 4; ++tc) {
              const float p = EXP2F(sc[z][tc][r] + bv);
              lpart[z][r] += p;
              const int pc = (tc * 2 + (ln >> 3)) ^ ((q * 4 + r) & 7);
              Ps[wave][(q * 4 + r) * 64 + pc * 8 + (ln & 7)] = (bf16_t)p;
            }
          }
        } else {
#pragma unroll
          for (int r = 0; r < 4; ++r) {
            const int rloc = m0 + q * 4 + r;
            const int dbase = rg0 + rloc - krb;
#pragma unroll
            for (int tc = 0; tc < 4; ++tc) {
              const int sl = tc * 16 + ln;
              const int d = dbase - sl;
              const bool valid = (jj < qt) | (d >= 0);
              int n = d < 0 ? 0 : d;
              if (z > 0) n += 1;
              const float bv = (float)biasS[z][rloc * 33 + bucket_of(n)];
              const float p = valid ? EXP2F(sc[z][tc][r] + bv) : 0.f;
              lpart[z][r] += p;
              const int pc = (tc * 2 + (ln >> 3)) ^ ((q * 4 + r) & 7);
              Ps[wave][(q * 4 + r) * 64 + pc * 8 + (ln & 7)] = (bf16_t)p;
            }
          }
        }

        bf16x8 ap[2];
        ap[0] = *(const bf16x8*)&Ps[wave][ln * 64 + co[0]];
        ap[1] = *(const bf16x8*)&Ps[wave][ln * 64 + co[1]];
#pragma unroll
        for (int tc = 0; tc < 4; ++tc) {
          Od[z][tc] = __builtin_amdgcn_mfma_f32_16x16x32_bf16(ap[0], vf[tc][0], Od[z][tc], 0, 0, 0);
          Od[z][tc] = __builtin_amdgcn_mfma_f32_16x16x32_bf16(ap[1], vf[tc][1], Od[z][tc], 0, 0, 0);
        }
      }
    } else {
      // diagonal predict tile: only stream z == jj - qt
#pragma unroll
      for (int z = 1; z <= 2; ++z) {
        if (jj - qt == z) {
          f32x4 acc[4];
#pragma unroll
          for (int tc = 0; tc < 4; ++tc)
#pragma unroll
            for (int r = 0; r < 4; ++r) acc[tc][r] = 0.f;
#pragma unroll
          for (int tc = 0; tc < 4; ++tc) {
            acc[tc] = __builtin_amdgcn_mfma_f32_16x16x32_bf16(aq[z][0], kf[tc][0], acc[tc], 0, 0, 0);
            acc[tc] = __builtin_amdgcn_mfma_f32_16x16x32_bf16(aq[z][1], kf[tc][1], acc[tc], 0, 0, 0);
          }
#pragma unroll
          for (int r = 0; r < 4; ++r) {
            const int rloc = m0 + q * 4 + r;
            const int rtile = rh * 32 + rloc;   // row within the 64-row tile
            const float bv = bv0[z][r];
#pragma unroll
            for (int tc = 0; tc < 4; ++tc) {
              const int sl = tc * 16 + ln;
              const float p = (sl == rtile) ? EXP2F(acc[tc][r] + bv) : 0.f;
              lpart[z][r] += p;
              const int pc = (tc * 2 + (ln >> 3)) ^ ((q * 4 + r) & 7);
              Ps[wave][(q * 4 + r) * 64 + pc * 8 + (ln & 7)] = (bf16_t)p;
            }
          }
          bf16x8 ap[2];
          ap[0] = *(const bf16x8*)&Ps[wave][ln * 64 + co[0]];
          ap[1] = *(const bf16x8*)&Ps[wave][ln * 64 + co[1]];
#pragma unroll
          for (int tc = 0; tc < 4; ++tc) {
            Od[z][tc] = __builtin_amdgcn_mfma_f32_16x16x32_bf16(ap[0], vf[tc][0], Od[z][tc], 0, 0, 0);
            Od[z][tc] = __builtin_amdgcn_mfma_f32_16x16x32_bf16(ap[1], vf[tc][1], Od[z][tc], 0, 0, 0);
          }
        }
      }
    }
    __syncthreads();        // all waves done reading Ks/Vts
    if (jj + 1 < ntiles) stage_tile(jj + 1);
  }

  // epilogue: reduce row sums, normalize, store
#pragma unroll
  for (int z = 0; z < 3; ++z) {
#pragma unroll
    for (int r = 0; r < 4; ++r) {
      float l = lpart[z][r];
      l += __shfl_xor(l, 1, 16);
      l += __shfl_xor(l, 2, 16);
      l += __shfl_xor(l, 4, 16);
      l += __shfl_xor(l, 8, 16);
      const float inv = 1.f / l;
      const size_t rowbase =
          ((size_t)(z * T_ + rg0 + m0 + q * 4 + r) * B_ + b) * (size_t)E_ + h * 64;
#pragma unroll
      for (int tc = 0; tc < 4; ++tc)
        attn[rowbase + tc * 16 + ln] = (bf16_t)(Od[z][tc][r] * inv);
    }
  }
}

// ---------------------------------------------------------------------------
extern "C" void kernel_launch(void* const* d_in, const int* in_sizes, int n_in,
                              void* d_out, int out_size, void* d_ws, size_t ws_size,
                              hipStream_t stream) {
  const float* query = (const float*)d_in[0];
  const float* ipw   = (const float*)d_in[1];
  const float* ipb   = (const float*)d_in[2];
  const float* relw  = (const float*)d_in[3];
  const float* relb  = (const float*)d_in[4];
  const float* outw  = (const float*)d_in[5];
  const float* outb  = (const float*)d_in[6];
  float* out = (float*)d_out;

  bf16_t* qkvb  = (bf16_t*)d_ws;                                 // 6144x3072
  float*  relv2 = (float*)(qkvb + (size_t)ROWS_ * 3 * E_);       // 6144x512 f32
  bf16_t* qb    = (bf16_t*)(relv2 + (size_t)ROWS_ * 512);        // 6144x1024
  bf16_t* ipwb  = qb + (size_t)ROWS_ * E_;                       // 3072x1024
  bf16_t* relwb = ipwb + (size_t)(3 * E_) * E_;                  // 512x1024 (adjacent!)
  bf16_t* outwb = relwb + (size_t)512 * E_;                      // 1024x1024
  bf16_t* attnb = outwb + (size_t)E_ * E_;                       // 6144x1024
  bf16_t* vT    = attnb + (size_t)ROWS_ * E_;                    // 64x64x1536

  const dim3 blk(256);

  // 1) conversions
  {
    const int ntot = (ROWS_ * E_ + 3 * E_ * E_ + 512 * E_ + E_ * E_) / 4;
    prep<<<dim3((ntot + 255) / 256), blk, 0, stream>>>(
        query, ipw, relw, outw, qb, ipwb, relwb, outwb);
  }

  // 2a) Q+K projection: 256 blocks = exactly 1 full round
  bgemm_proj<<<dim3(8, 32), dim3(512), 0, stream>>>(
      qb, ipwb, ipb, relb, qkvb, relv2, vT, 0);
  // 2b) V + rel projection: 192 blocks = 1 round at 75%
  bgemm_proj<<<dim3(6, 32), dim3(512), 0, stream>>>(
      qb, ipwb, ipb, relb, qkvb, relv2, vT, 2048);

  // 3) flash attention: 1024 x 128-thread blocks, 3 waves/SIMD occupancy
  flash_mfma<<<dim3(64, 16), dim3(128), 0, stream>>>(
      qkvb, vT, relv2, attnb);

  // 4) output projection: 256 blocks = exactly 1 round
  bgemm_out<<<dim3(8, 32), blk, 0, stream>>>(
      attnb, outwb, outb, out);
}

// Round 10
// 247.170 us; speedup vs baseline: 1.6029x; 1.6029x over previous
//
#include <hip/hip_runtime.h>
#include <hip/hip_bf16.h>
#include <math.h>

// Problem constants
constexpr int T_ = 512;
constexpr int B_ = 4;
constexpr int E_ = 1024;
constexpr int H_ = 16;
constexpr int NGRAM_ = 2;
constexpr int TGT_ = (1 + NGRAM_) * T_;   // 1536
constexpr int ROWS_ = TGT_ * B_;          // 6144

typedef __bf16 bf16_t;
typedef __bf16 bf16x8 __attribute__((ext_vector_type(8)));
typedef __bf16 bf16x4 __attribute__((ext_vector_type(4)));
typedef float f32x4 __attribute__((ext_vector_type(4)));

#define GLL(gaddr, laddr)                                                     \
  __builtin_amdgcn_global_load_lds(                                           \
      (const __attribute__((address_space(1))) void*)(gaddr),                 \
      (__attribute__((address_space(3))) void*)(laddr), 16, 0, 0)

// raw barrier / counted waits: asm with memory clobber = compiler fence,
// no compiler-inserted vmcnt(0) drain (unlike __syncthreads()).
#define BARX()   asm volatile("s_barrier" ::: "memory")
#define WVM7()   asm volatile("s_waitcnt vmcnt(7)" ::: "memory")
#define WVM10()  asm volatile("s_waitcnt vmcnt(10)" ::: "memory")
#define WVM0()   asm volatile("s_waitcnt vmcnt(0)" ::: "memory")

constexpr float LOG2E_ = 1.44269504088896f;
#define EXP2F(x) __builtin_amdgcn_exp2f(x)

// ---------------------------------------------------------------------------
// prep: all fp32->bf16 conversions, one launch.
// ---------------------------------------------------------------------------
__global__ __launch_bounds__(256) void prep(
    const float* __restrict__ query, const float* __restrict__ ipw,
    const float* __restrict__ relw, const float* __restrict__ outw,
    bf16_t* __restrict__ qb, bf16_t* __restrict__ ipwb,
    bf16_t* __restrict__ relwb, bf16_t* __restrict__ outwb) {
  const int i = blockIdx.x * 256 + threadIdx.x;
  constexpr int N1 = ROWS_ * E_ / 4;
  constexpr int N2 = 3 * E_ * E_ / 4;
  constexpr int N3 = 512 * E_ / 4;
  constexpr int N4 = E_ * E_ / 4;
  const float4* src;
  bf16_t* dst;
  int j = i;
  if (i < N1) { src = (const float4*)query; dst = qb; }
  else if (i < N1 + N2) { src = (const float4*)ipw; dst = ipwb; j = i - N1; }
  else if (i < N1 + N2 + N3) { src = (const float4*)relw; dst = relwb; j = i - N1 - N2; }
  else if (i < N1 + N2 + N3 + N4) { src = (const float4*)outw; dst = outwb; j = i - N1 - N2 - N3; }
  else return;
  const float4 v = src[j];
  bf16x4 o;
  o[0] = (bf16_t)v.x; o[1] = (bf16_t)v.y;
  o[2] = (bf16_t)v.z; o[3] = (bf16_t)v.w;
  ((bf16x4*)dst)[j] = o;
}

// ---------------------------------------------------------------------------
// Combined projection GEMM, BM=192 x BN=256 x BK=64, 512 threads, r2
// schedule, split in two dispatches. Q is scaled by 0.125*log2(e) so the
// attention softmax can use exp2 directly (exp(x) == exp2(x*log2e)).
// ---------------------------------------------------------------------------
__device__ __forceinline__ int sw256(int row, int col) {
  // XOR-swizzled bounce layout for the 192x256 V-tile transpose
  return row * 256 + ((((col >> 3) ^ (row & 31)) << 3) | (col & 7));
}

__global__ __launch_bounds__(512, 2) void bgemm_proj(
    const bf16_t* __restrict__ A, const bf16_t* __restrict__ W,
    const float* __restrict__ ipb, const float* __restrict__ relb,
    bf16_t* __restrict__ qkvb, float* __restrict__ relv2,
    bf16_t* __restrict__ vT, int bn0) {
  // [As0|As1] 2x192x64, [Bs0|Bs1] 2x256x64  (112 KB total)
  __shared__ bf16_t smem[57344];
  bf16_t* As0 = smem;
  bf16_t* As1 = smem + 12288;
  bf16_t* Bs0 = smem + 24576;
  bf16_t* Bs1 = smem + 24576 + 16384;

  const int tid = threadIdx.x;
  const int wave = tid >> 6, lane = tid & 63;
  const int wr = wave >> 2, wc = wave & 3;       // 2 x 4 wave grid
  // bijective XCD swizzle; nwg is 256 or 192, both divisible by 8.
  const int nx = gridDim.x;
  const int pid = blockIdx.y * nx + blockIdx.x;
  const int chunk = (nx * gridDim.y) >> 3;
  const int lid = (pid & 7) * chunk + (pid >> 3);
  const int by = lid / nx;
  const int bx = lid - by * nx;
  const int bm = by * 192, bn = bn0 + bx * 256;
  const int q = lane >> 4, ln = lane & 15;
  const int grow = tid >> 3;                              // 0..63
  const int gcol = ((tid & 7) ^ (grow & 7)) * 8;          // pre-swizzled src
  const int co[2] = {((q) ^ (ln & 7)) * 8, ((4 + q) ^ (ln & 7)) * 8};

  f32x4 acc[6][4];
#pragma unroll
  for (int mi = 0; mi < 6; ++mi)
#pragma unroll
    for (int ni = 0; ni < 4; ++ni)
#pragma unroll
      for (int r = 0; r < 4; ++r) acc[mi][ni][r] = 0.f;

  // stage one K-tile (7 GLL per thread: 3 A-rounds + 4 B-rounds of 64 rows)
  auto stage = [&](int kt, bf16_t* la, bf16_t* lb) {
    const int kc = kt * 64 + gcol;
#pragma unroll
    for (int p = 0; p < 3; ++p)
      GLL(&A[(size_t)(bm + p * 64 + grow) * 1024 + kc], &la[p * 4096 + tid * 8]);
#pragma unroll
    for (int p = 0; p < 4; ++p)
      GLL(&W[(size_t)(bn + p * 64 + grow) * 1024 + kc], &lb[p * 4096 + tid * 8]);
  };

  // One K-tile, barrier-free inside: reads prefetched 1 sub-phase deep.
  auto compute_tile = [&](const bf16_t* la, const bf16_t* lb) {
    bf16x8 a0[3], a1[3], b0[4], b1[4];
#pragma unroll
    for (int ni = 0; ni < 4; ++ni)
      b0[ni] = *(const bf16x8*)&lb[(wc * 64 + ni * 16 + ln) * 64 + co[0]];
#pragma unroll
    for (int mi = 0; mi < 3; ++mi)
      a0[mi] = *(const bf16x8*)&la[(wr * 96 + mi * 16 + ln) * 64 + co[0]];
#pragma unroll
    for (int mi = 0; mi < 3; ++mi)
      a1[mi] = *(const bf16x8*)&la[(wr * 96 + (3 + mi) * 16 + ln) * 64 + co[0]];
    __builtin_amdgcn_s_setprio(1);
#pragma unroll
    for (int mi = 0; mi < 3; ++mi)
#pragma unroll
      for (int ni = 0; ni < 4; ++ni)
        acc[mi][ni] = __builtin_amdgcn_mfma_f32_16x16x32_bf16(
            a0[mi], b0[ni], acc[mi][ni], 0, 0, 0);
    __builtin_amdgcn_s_setprio(0);
#pragma unroll
    for (int ni = 0; ni < 4; ++ni)
      b1[ni] = *(const bf16x8*)&lb[(wc * 64 + ni * 16 + ln) * 64 + co[1]];
#pragma unroll
    for (int mi = 0; mi < 3; ++mi)
      a0[mi] = *(const bf16x8*)&la[(wr * 96 + mi * 16 + ln) * 64 + co[1]];
    __builtin_amdgcn_s_setprio(1);
#pragma unroll
    for (int mi = 0; mi < 3; ++mi)
#pragma unroll
      for (int ni = 0; ni < 4; ++ni)
        acc[3 + mi][ni] = __builtin_amdgcn_mfma_f32_16x16x32_bf16(
            a1[mi], b0[ni], acc[3 + mi][ni], 0, 0, 0);
    __builtin_amdgcn_s_setprio(0);
#pragma unroll
    for (int mi = 0; mi < 3; ++mi)
      a1[mi] = *(const bf16x8*)&la[(wr * 96 + (3 + mi) * 16 + ln) * 64 + co[1]];
    __builtin_amdgcn_s_setprio(1);
#pragma unroll
    for (int mi = 0; mi < 3; ++mi)
#pragma unroll
      for (int ni = 0; ni < 4; ++ni)
        acc[mi][ni] = __builtin_amdgcn_mfma_f32_16x16x32_bf16(
            a0[mi], b1[ni], acc[mi][ni], 0, 0, 0);
    __builtin_amdgcn_s_setprio(0);
    __builtin_amdgcn_s_setprio(1);
#pragma unroll
    for (int mi = 0; mi < 3; ++mi)
#pragma unroll
      for (int ni = 0; ni < 4; ++ni)
        acc[3 + mi][ni] = __builtin_amdgcn_mfma_f32_16x16x32_bf16(
            a1[mi], b1[ni], acc[3 + mi][ni], 0, 0, 0);
    __builtin_amdgcn_s_setprio(0);
  };

  // prologue: 2 K-tiles in flight (14 outstanding GLL per thread)
  stage(0, As0, Bs0);
  stage(1, As1, Bs1);

  for (int kt = 0; kt < 16; kt += 2) {
    WVM7(); BARX();                       // tile kt resident for all waves
    compute_tile(As0, Bs0);
    BARX();                               // all waves done reading buf0
    if (kt + 2 < 16) stage(kt + 2, As0, Bs0);
    if (kt < 14) { WVM7(); } else { WVM0(); }   // tile kt+1 resident
    BARX();
    compute_tile(As1, Bs1);
    BARX();                               // all waves done reading buf1
    if (kt + 3 < 16) stage(kt + 3, As1, Bs1);
  }

  // ---------------- epilogue (per-block uniform routing) -------------------
  if (bn < 2048) {
    // Q (scaled by 0.125*log2e for exp2 softmax) and K -> qkvb
    const float sc = (bn < 1024) ? 0.125f * LOG2E_ : 1.0f;
#pragma unroll
    for (int mi = 0; mi < 6; ++mi) {
#pragma unroll
      for (int ni = 0; ni < 4; ++ni) {
        const int col = bn + wc * 64 + ni * 16 + ln;
        const float bv = ipb[col];
#pragma unroll
        for (int r = 0; r < 4; ++r) {
          const int row = bm + wr * 96 + mi * 16 + q * 4 + r;
          qkvb[(size_t)row * 3072 + col] = (bf16_t)((acc[mi][ni][r] + bv) * sc);
        }
      }
    }
  } else if (bn < 3072) {
    // V: transpose in-block via swizzled LDS bounce, write vT[bh][d][token]
    __syncthreads();  // K-loop LDS fully drained; reuse smem as bounce
#pragma unroll
    for (int mi = 0; mi < 6; ++mi) {
#pragma unroll
      for (int ni = 0; ni < 4; ++ni) {
        const int col_l = wc * 64 + ni * 16 + ln;
        const float bv = ipb[bn + col_l];
#pragma unroll
        for (int r = 0; r < 4; ++r) {
          const int row_l = wr * 96 + mi * 16 + q * 4 + r;
          smem[sw256(row_l, col_l)] = (bf16_t)(acc[mi][ni][r] + bv);
        }
      }
    }
    __syncthreads();
    const int h0 = (bn - 2048) >> 6;     // 4 heads per 256-col tile
    const int tb0 = bm >> 2;             // 48 tokens per 192-row tile
#pragma unroll
    for (int e = 0; e < 2; ++e) {
      const int task = e * 512 + tid;    // 1024 tasks: (b, col)
      const int b = task & 3;
      const int c = task >> 2;           // 0..255
      const int h = h0 + (c >> 6);
      const int d = c & 63;
      const size_t base = ((size_t)((b * 16 + h) * 64 + d)) * (size_t)TGT_ + tb0;
#pragma unroll
      for (int k = 0; k < 6; ++k) {
        bf16x8 v8;
#pragma unroll
        for (int i = 0; i < 8; ++i)
          v8[i] = smem[sw256((k * 8 + i) * 4 + b, c)];
        *(bf16x8*)&vT[base + k * 8] = v8;
      }
    }
  } else {
    const int cb = bn - 3072 + wc * 64;
    float4 rb4;
#pragma unroll
    for (int ni = 0; ni < 4; ++ni)
      ((float*)&rb4)[ni] = relb[cb + ni * 16 + ln];
    const int bkbase = cb >> 4;
#pragma unroll
    for (int mi = 0; mi < 6; ++mi) {
#pragma unroll
      for (int r = 0; r < 4; ++r) {
        const int row = bm + wr * 96 + mi * 16 + q * 4 + r;
        float4 v;
        v.x = acc[mi][0][r] + rb4.x;
        v.y = acc[mi][1][r] + rb4.y;
        v.z = acc[mi][2][r] + rb4.z;
        v.w = acc[mi][3][r] + rb4.w;
        *(float4*)&relv2[(size_t)row * 512 + ln * 32 + bkbase] = v;
      }
    }
  }
}

// ---------------------------------------------------------------------------
// Output projection GEMM (fp32 out). BM=192 x BN=128, 256 threads, dbuf
// 80 KB LDS, grid 8x32 = 256 blocks = exactly 1 block/CU, single round.
// ---------------------------------------------------------------------------
__global__ __launch_bounds__(256, 1) void bgemm_out(
    const bf16_t* __restrict__ A, const bf16_t* __restrict__ W,
    const float* __restrict__ bias, float* __restrict__ C) {
  // slot s: A at s*20480 (192x64), B at s*20480+12288 (128x64); 80 KB
  __shared__ bf16_t smem[40960];

  const int tid = threadIdx.x;
  const int wave = tid >> 6, lane = tid & 63;
  const int wr = wave >> 1, wc = wave & 1;        // 2x2 wave grid
  const int pid = blockIdx.y * 8 + blockIdx.x;    // 256 = 8*32
  const int lid = (pid & 7) * 32 + (pid >> 3);
  const int bm = (lid >> 3) * 192, bn = (lid & 7) * 128;
  const int q = lane >> 4, ln = lane & 15;
  const int grow = tid >> 3;                      // 0..31
  const int gcol = ((tid & 7) ^ (grow & 7)) * 8;
  const int co[2] = {((q) ^ (ln & 7)) * 8, ((4 + q) ^ (ln & 7)) * 8};

  f32x4 acc[6][4];
#pragma unroll
  for (int mi = 0; mi < 6; ++mi)
#pragma unroll
    for (int ni = 0; ni < 4; ++ni)
#pragma unroll
      for (int r = 0; r < 4; ++r) acc[mi][ni][r] = 0.f;

  // 10 GLL per thread per tile: A 6 rounds of 32 rows, B 4 rounds.
  auto stage = [&](int kt) {
    bf16_t* s = smem + (kt & 1) * 20480;
    const int kc = kt * 64 + gcol;
#pragma unroll
    for (int p = 0; p < 6; ++p)
      GLL(&A[(size_t)(bm + p * 32 + grow) * 1024 + kc], &s[p * 2048 + tid * 8]);
#pragma unroll
    for (int p = 0; p < 4; ++p)
      GLL(&W[(size_t)(bn + p * 32 + grow) * 1024 + kc],
          &s[12288 + p * 2048 + tid * 8]);
  };

  auto compute_tile = [&](int kt) {
    const bf16_t* la = smem + (kt & 1) * 20480;
    const bf16_t* lb = la + 12288;
    bf16x8 a0[3], a1[3], b0[4], b1[4];
#pragma unroll
    for (int ni = 0; ni < 4; ++ni)
      b0[ni] = *(const bf16x8*)&lb[(wc * 64 + ni * 16 + ln) * 64 + co[0]];
#pragma unroll
    for (int mi = 0; mi < 3; ++mi)
      a0[mi] = *(const bf16x8*)&la[(wr * 96 + mi * 16 + ln) * 64 + co[0]];
#pragma unroll
    for (int mi = 0; mi < 3; ++mi)
      a1[mi] = *(const bf16x8*)&la[(wr * 96 + (3 + mi) * 16 + ln) * 64 + co[0]];
    __builtin_amdgcn_s_setprio(1);
#pragma unroll
    for (int mi = 0; mi < 3; ++mi)
#pragma unroll
      for (int ni = 0; ni < 4; ++ni)
        acc[mi][ni] = __builtin_amdgcn_mfma_f32_16x16x32_bf16(
            a0[mi], b0[ni], acc[mi][ni], 0, 0, 0);
    __builtin_amdgcn_s_setprio(0);
#pragma unroll
    for (int ni = 0; ni < 4; ++ni)
      b1[ni] = *(const bf16x8*)&lb[(wc * 64 + ni * 16 + ln) * 64 + co[1]];
#pragma unroll
    for (int mi = 0; mi < 3; ++mi)
      a0[mi] = *(const bf16x8*)&la[(wr * 96 + mi * 16 + ln) * 64 + co[1]];
    __builtin_amdgcn_s_setprio(1);
#pragma unroll
    for (int mi = 0; mi < 3; ++mi)
#pragma unroll
      for (int ni = 0; ni < 4; ++ni)
        acc[3 + mi][ni] = __builtin_amdgcn_mfma_f32_16x16x32_bf16(
            a1[mi], b0[ni], acc[3 + mi][ni], 0, 0, 0);
    __builtin_amdgcn_s_setprio(0);
#pragma unroll
    for (int mi = 0; mi < 3; ++mi)
      a1[mi] = *(const bf16x8*)&la[(wr * 96 + (3 + mi) * 16 + ln) * 64 + co[1]];
    __builtin_amdgcn_s_setprio(1);
#pragma unroll
    for (int mi = 0; mi < 3; ++mi)
#pragma unroll
      for (int ni = 0; ni < 4; ++ni)
        acc[mi][ni] = __builtin_amdgcn_mfma_f32_16x16x32_bf16(
            a0[mi], b1[ni], acc[mi][ni], 0, 0, 0);
    __builtin_amdgcn_s_setprio(0);
    __builtin_amdgcn_s_setprio(1);
#pragma unroll
    for (int mi = 0; mi < 3; ++mi)
#pragma unroll
      for (int ni = 0; ni < 4; ++ni)
        acc[3 + mi][ni] = __builtin_amdgcn_mfma_f32_16x16x32_bf16(
            a1[mi], b1[ni], acc[3 + mi][ni], 0, 0, 0);
    __builtin_amdgcn_s_setprio(0);
  };

  stage(0);
  stage(1);

  for (int kt = 0; kt < 16; kt += 2) {
    WVM10(); BARX();                      // tile kt resident
    compute_tile(kt);
    BARX();
    if (kt + 2 < 16) stage(kt + 2);
    if (kt < 14) { WVM10(); } else { WVM0(); }  // tile kt+1 resident
    BARX();
    compute_tile(kt + 1);
    BARX();
    if (kt + 3 < 16) stage(kt + 3);
  }

#pragma unroll
  for (int mi = 0; mi < 6; ++mi) {
#pragma unroll
    for (int ni = 0; ni < 4; ++ni) {
      const int col = bn + wc * 64 + ni * 16 + ln;
      const float bv = bias[col];
#pragma unroll
      for (int r = 0; r < 4; ++r) {
        const int row = bm + wr * 96 + mi * 16 + q * 4 + r;
        C[(size_t)row * 1024 + col] = acc[mi][ni][r] + bv;
      }
    }
  }
}

// ---------------------------------------------------------------------------
// MFMA flash attention. ROUND-10: r9 geometry with the SPILL fixed.
// r9's __launch_bounds__(128,3) made regalloc target 84 VGPR -> ~290 MB
// scratch traffic, 4x slowdown. Fix: (a) no min-waves hint (natural alloc,
// occupancy comes from the 27 KB LDS limit = 6 blocks/CU = 3 waves/SIMD);
// (b) z-sequential QK->softmax->PV (acc[4], not sc[3][4]: -32 VGPR
// pressure; r7 measured the hoist at ~0 gain anyway).
// ---------------------------------------------------------------------------
__device__ __forceinline__ int bucket_of(int n) {
  if (n < 16) return n;
  const float lf = __log2f((float)n);
  int b = (int)(16.0f + (lf - 4.0f) * 5.3333333f);
  return b > 31 ? 31 : b;
}

__global__ __launch_bounds__(128) void flash_mfma(
    const bf16_t* __restrict__ qkvb, const bf16_t* __restrict__ vT,
    const float* __restrict__ relv2, bf16_t* __restrict__ attn) {
  __shared__ bf16_t Ks[64 * 64];        // K tile (also Q z0/z1 in prologue)
  __shared__ bf16_t Vts[64 * 64];       // V^T tile (also Q z2 in prologue)
  __shared__ bf16_t Ps[2][16 * 64];
  __shared__ bf16_t biasS[3][32 * 33];

  const int bh = blockIdx.x;            // fast dim: uniform per XCD
  const int yy = blockIdx.y;            // 0..15
  const int rh = yy & 1;                // Q-row half
  const int qy = yy >> 1;
  const int qt = (qy < 4) ? (7 - qy) : (qy - 4);   // complementary pairs
  const int tq0 = qt * 64;
  const int rg0 = tq0 + rh * 32;        // global first Q-row of this block
  const int b = bh >> 4, h = bh & 15;
  const int tid = threadIdx.x;
  const int wave = tid >> 6, lane = tid & 63;
  const int q = lane >> 4, ln = lane & 15;
  const int m0 = wave * 16;             // local row base (0 or 16) within 32
  const int grow = tid >> 3;            // 0..15
  const int gcol = ((tid & 7) ^ (grow & 7)) * 8;
  const int co[2] = {((q) ^ (ln & 7)) * 8, ((4 + q) ^ (ln & 7)) * 8};

  // stage bias rows for this block's 32 Q-rows, scaled by log2e (exp2 path)
#pragma unroll
  for (int z = 0; z < 3; ++z) {
#pragma unroll
    for (int u = 0; u < 2; ++u) {
      const int c = u * 128 + tid;      // 0..255
      const int row = c >> 3, j4 = (c & 7) * 4;
      const float4 v = *(const float4*)
          &relv2[((size_t)(z * T_ + rg0 + row) * B_ + b) * 512 + h * 32 + j4];
      biasS[z][row * 33 + j4 + 0] = (bf16_t)(v.x * LOG2E_);
      biasS[z][row * 33 + j4 + 1] = (bf16_t)(v.y * LOG2E_);
      biasS[z][row * 33 + j4 + 2] = (bf16_t)(v.z * LOG2E_);
      biasS[z][row * 33 + j4 + 3] = (bf16_t)(v.w * LOG2E_);
    }
  }

  // stage the three 32-row Q tiles (z0 -> Ks[0:32], z1 -> Ks[32:64], z2 -> Vts)
#pragma unroll
  for (int u = 0; u < 2; ++u) {
    const int sr = u * 16 + grow;
    GLL(&qkvb[((size_t)(0 * T_ + rg0 + sr) * B_ + b) * 3072 + h * 64 + gcol],
        &Ks[u * 1024 + tid * 8]);
    GLL(&qkvb[((size_t)(1 * T_ + rg0 + sr) * B_ + b) * 3072 + h * 64 + gcol],
        &Ks[2048 + u * 1024 + tid * 8]);
    GLL(&qkvb[((size_t)(2 * T_ + rg0 + sr) * B_ + b) * 3072 + h * 64 + gcol],
        &Vts[u * 1024 + tid * 8]);
  }
  __syncthreads();

  bf16x8 aq[3][2];
  aq[0][0] = *(const bf16x8*)&Ks[(m0 + ln) * 64 + co[0]];
  aq[0][1] = *(const bf16x8*)&Ks[(m0 + ln) * 64 + co[1]];
  aq[1][0] = *(const bf16x8*)&Ks[(32 + m0 + ln) * 64 + co[0]];
  aq[1][1] = *(const bf16x8*)&Ks[(32 + m0 + ln) * 64 + co[1]];
  aq[2][0] = *(const bf16x8*)&Vts[(m0 + ln) * 64 + co[0]];
  aq[2][1] = *(const bf16x8*)&Vts[(m0 + ln) * 64 + co[1]];

  float bv31[3][4], bv0[3][4];
#pragma unroll
  for (int z = 0; z < 3; ++z)
#pragma unroll
    for (int r = 0; r < 4; ++r) {
      const int rloc = m0 + q * 4 + r;
      bv31[z][r] = (float)biasS[z][rloc * 33 + 31];
      bv0[z][r] = (float)biasS[z][rloc * 33];
    }

  f32x4 Od[3][4];
  float lpart[3][4];
#pragma unroll
  for (int z = 0; z < 3; ++z)
#pragma unroll
    for (int r = 0; r < 4; ++r) {
      lpart[z][r] = 0.f;
#pragma unroll
      for (int tc = 0; tc < 4; ++tc) Od[z][tc][r] = 0.f;
    }

  const int ntiles = qt + 3;

  // single-buffered K/V staging: full 64-token tile (8 GLL per thread)
  auto stage_tile = [&](int jj) {
    const int krb = (jj <= qt) ? jj * 64 : ((jj - qt) * T_ + tq0);
#pragma unroll
    for (int u = 0; u < 4; ++u) {
      const int sr = u * 16 + grow;
      GLL(&qkvb[((size_t)(krb + sr) * B_ + b) * 3072 + 1024 + h * 64 + gcol],
          &Ks[u * 1024 + tid * 8]);
      GLL(&vT[((size_t)bh * 64 + sr) * (size_t)TGT_ + krb + gcol],
          &Vts[u * 1024 + tid * 8]);
    }
  };

  __syncthreads();          // aq reads complete before overwriting buffers
  stage_tile(0);

  for (int jj = 0; jj < ntiles; ++jj) {
    __syncthreads();        // vmcnt+lgkm drained + barrier: tile jj resident

    const int krb = (jj <= qt) ? jj * 64 : ((jj - qt) * T_ + tq0);

    bf16x8 kf[4][2], vf[4][2];
#pragma unroll
    for (int tc = 0; tc < 4; ++tc) {
      kf[tc][0] = *(const bf16x8*)&Ks[(tc * 16 + ln) * 64 + co[0]];
      kf[tc][1] = *(const bf16x8*)&Ks[(tc * 16 + ln) * 64 + co[1]];
      vf[tc][0] = *(const bf16x8*)&Vts[(tc * 16 + ln) * 64 + co[0]];
      vf[tc][1] = *(const bf16x8*)&Vts[(tc * 16 + ln) * 64 + co[1]];
    }

    if (jj <= qt) {
      const bool far = (jj <= qt - 3);
      // per-z sequential: QK^T -> softmax (exp2) -> Ps -> PV
#pragma unroll
      for (int z = 0; z < 3; ++z) {
        f32x4 acc[4];
#pragma unroll
        for (int tc = 0; tc < 4; ++tc)
#pragma unroll
          for (int r = 0; r < 4; ++r) acc[tc][r] = 0.f;
#pragma unroll
        for (int tc = 0; tc < 4; ++tc) {
          acc[tc] = __builtin_amdgcn_mfma_f32_16x16x32_bf16(aq[z][0], kf[tc][0], acc[tc], 0, 0, 0);
          acc[tc] = __builtin_amdgcn_mfma_f32_16x16x32_bf16(aq[z][1], kf[tc][1], acc[tc], 0, 0, 0);
        }

        if (far) {
#pragma unroll
          for (int r = 0; r < 4; ++r) {
            const float bv = bv31[z][r];
#pragma unroll
            for (int tc = 0; tc < 4; ++tc) {
              const float p = EXP2F(acc[tc][r] + bv);
              lpart[z][r] += p;
              const int pc = (tc * 2 + (ln >> 3)) ^ ((q * 4 + r) & 7);
              Ps[wave][(q * 4 + r) * 64 + pc * 8 + (ln & 7)] = (bf16_t)p;
            }
          }
        } else {
#pragma unroll
          for (int r = 0; r < 4; ++r) {
            const int rloc = m0 + q * 4 + r;
            const int dbase = rg0 + rloc - krb;
#pragma unroll
            for (int tc = 0; tc < 4; ++tc) {
              const int sl = tc * 16 + ln;
              const int d = dbase - sl;
              const bool valid = (jj < qt) | (d >= 0);
              int n = d < 0 ? 0 : d;
              if (z > 0) n += 1;
              const float bv = (float)biasS[z][rloc * 33 + bucket_of(n)];
              const float p = valid ? EXP2F(acc[tc][r] + bv) : 0.f;
              lpart[z][r] += p;
              const int pc = (tc * 2 + (ln >> 3)) ^ ((q * 4 + r) & 7);
              Ps[wave][(q * 4 + r) * 64 + pc * 8 + (ln & 7)] = (bf16_t)p;
            }
          }
        }

        bf16x8 ap[2];
        ap[0] = *(const bf16x8*)&Ps[wave][ln * 64 + co[0]];
        ap[1] = *(const bf16x8*)&Ps[wave][ln * 64 + co[1]];
#pragma unroll
        for (int tc = 0; tc < 4; ++tc) {
          Od[z][tc] = __builtin_amdgcn_mfma_f32_16x16x32_bf16(ap[0], vf[tc][0], Od[z][tc], 0, 0, 0);
          Od[z][tc] = __builtin_amdgcn_mfma_f32_16x16x32_bf16(ap[1], vf[tc][1], Od[z][tc], 0, 0, 0);
        }
      }
    } else {
      // diagonal predict tile: only stream z == jj - qt
#pragma unroll
      for (int z = 1; z <= 2; ++z) {
        if (jj - qt == z) {
          f32x4 acc[4];
#pragma unroll
          for (int tc = 0; tc < 4; ++tc)
#pragma unroll
            for (int r = 0; r < 4; ++r) acc[tc][r] = 0.f;
#pragma unroll
          for (int tc = 0; tc < 4; ++tc) {
            acc[tc] = __builtin_amdgcn_mfma_f32_16x16x32_bf16(aq[z][0], kf[tc][0], acc[tc], 0, 0, 0);
            acc[tc] = __builtin_amdgcn_mfma_f32_16x16x32_bf16(aq[z][1], kf[tc][1], acc[tc], 0, 0, 0);
          }
#pragma unroll
          for (int r = 0; r < 4; ++r) {
            const int rloc = m0 + q * 4 + r;
            const int rtile = rh * 32 + rloc;   // row within the 64-row tile
            const float bv = bv0[z][r];
#pragma unroll
            for (int tc = 0; tc < 4; ++tc) {
              const int sl = tc * 16 + ln;
              const float p = (sl == rtile) ? EXP2F(acc[tc][r] + bv) : 0.f;
              lpart[z][r] += p;
              const int pc = (tc * 2 + (ln >> 3)) ^ ((q * 4 + r) & 7);
              Ps[wave][(q * 4 + r) * 64 + pc * 8 + (ln & 7)] = (bf16_t)p;
            }
          }
          bf16x8 ap[2];
          ap[0] = *(const bf16x8*)&Ps[wave][ln * 64 + co[0]];
          ap[1] = *(const bf16x8*)&Ps[wave][ln * 64 + co[1]];
#pragma unroll
          for (int tc = 0; tc < 4; ++tc) {
            Od[z][tc] = __builtin_amdgcn_mfma_f32_16x16x32_bf16(ap[0], vf[tc][0], Od[z][tc], 0, 0, 0);
            Od[z][tc] = __builtin_amdgcn_mfma_f32_16x16x32_bf16(ap[1], vf[tc][1], Od[z][tc], 0, 0, 0);
          }
        }
      }
    }
    __syncthreads();        // all waves done reading Ks/Vts
    if (jj + 1 < ntiles) stage_tile(jj + 1);
  }

  // epilogue: reduce row sums, normalize, store
#pragma unroll
  for (int z = 0; z < 3; ++z) {
#pragma unroll
    for (int r = 0; r < 4; ++r) {
      float l = lpart[z][r];
      l += __shfl_xor(l, 1, 16);
      l += __shfl_xor(l, 2, 16);
      l += __shfl_xor(l, 4, 16);
      l += __shfl_xor(l, 8, 16);
      const float inv = 1.f / l;
      const size_t rowbase =
          ((size_t)(z * T_ + rg0 + m0 + q * 4 + r) * B_ + b) * (size_t)E_ + h * 64;
#pragma unroll
      for (int tc = 0; tc < 4; ++tc)
        attn[rowbase + tc * 16 + ln] = (bf16_t)(Od[z][tc][r] * inv);
    }
  }
}

// ---------------------------------------------------------------------------
extern "C" void kernel_launch(void* const* d_in, const int* in_sizes, int n_in,
                              void* d_out, int out_size, void* d_ws, size_t ws_size,
                              hipStream_t stream) {
  const float* query = (const float*)d_in[0];
  const float* ipw   = (const float*)d_in[1];
  const float* ipb   = (const float*)d_in[2];
  const float* relw  = (const float*)d_in[3];
  const float* relb  = (const float*)d_in[4];
  const float* outw  = (const float*)d_in[5];
  const float* outb  = (const float*)d_in[6];
  float* out = (float*)d_out;

  bf16_t* qkvb  = (bf16_t*)d_ws;                                 // 6144x3072
  float*  relv2 = (float*)(qkvb + (size_t)ROWS_ * 3 * E_);       // 6144x512 f32
  bf16_t* qb    = (bf16_t*)(relv2 + (size_t)ROWS_ * 512);        // 6144x1024
  bf16_t* ipwb  = qb + (size_t)ROWS_ * E_;                       // 3072x1024
  bf16_t* relwb = ipwb + (size_t)(3 * E_) * E_;                  // 512x1024 (adjacent!)
  bf16_t* outwb = relwb + (size_t)512 * E_;                      // 1024x1024
  bf16_t* attnb = outwb + (size_t)E_ * E_;                       // 6144x1024
  bf16_t* vT    = attnb + (size_t)ROWS_ * E_;                    // 64x64x1536

  const dim3 blk(256);

  // 1) conversions
  {
    const int ntot = (ROWS_ * E_ + 3 * E_ * E_ + 512 * E_ + E_ * E_) / 4;
    prep<<<dim3((ntot + 255) / 256), blk, 0, stream>>>(
        query, ipw, relw, outw, qb, ipwb, relwb, outwb);
  }

  // 2a) Q+K projection: 256 blocks = exactly 1 full round
  bgemm_proj<<<dim3(8, 32), dim3(512), 0, stream>>>(
      qb, ipwb, ipb, relb, qkvb, relv2, vT, 0);
  // 2b) V + rel projection: 192 blocks = 1 round at 75%
  bgemm_proj<<<dim3(6, 32), dim3(512), 0, stream>>>(
      qb, ipwb, ipb, relb, qkvb, relv2, vT, 2048);

  // 3) flash attention: 1024 x 128-thread blocks, LDS-limited occupancy
  flash_mfma<<<dim3(64, 16), dim3(128), 0, stream>>>(
      qkvb, vT, relv2, attnb);

  // 4) output projection: 256 blocks = exactly 1 round
  bgemm_out<<<dim3(8, 32), blk, 0, stream>>>(
      attnb, outwb, outb, out);
}

// Round 11
// 232.285 us; speedup vs baseline: 1.7056x; 1.0641x over previous
//
#include <hip/hip_runtime.h>
#include <hip/hip_bf16.h>
#include <math.h>

// Problem constants
constexpr int T_ = 512;
constexpr int B_ = 4;
constexpr int E_ = 1024;
constexpr int H_ = 16;
constexpr int NGRAM_ = 2;
constexpr int TGT_ = (1 + NGRAM_) * T_;   // 1536
constexpr int ROWS_ = TGT_ * B_;          // 6144

typedef __bf16 bf16_t;
typedef __bf16 bf16x8 __attribute__((ext_vector_type(8)));
typedef __bf16 bf16x4 __attribute__((ext_vector_type(4)));
typedef float f32x4 __attribute__((ext_vector_type(4)));

#define GLL(gaddr, laddr)                                                     \
  __builtin_amdgcn_global_load_lds(                                           \
      (const __attribute__((address_space(1))) void*)(gaddr),                 \
      (__attribute__((address_space(3))) void*)(laddr), 16, 0, 0)

// raw barrier / counted waits: asm with memory clobber = compiler fence,
// no compiler-inserted vmcnt(0) drain (unlike __syncthreads()).
#define BARX()   asm volatile("s_barrier" ::: "memory")
#define WVM7()   asm volatile("s_waitcnt vmcnt(7)" ::: "memory")
#define WVM10()  asm volatile("s_waitcnt vmcnt(10)" ::: "memory")
#define WVM0()   asm volatile("s_waitcnt vmcnt(0)" ::: "memory")

constexpr float LOG2E_ = 1.44269504088896f;
#define EXP2F(x) __builtin_amdgcn_exp2f(x)

// ---------------------------------------------------------------------------
// prep: all fp32->bf16 conversions, one launch.
// ---------------------------------------------------------------------------
__global__ __launch_bounds__(256) void prep(
    const float* __restrict__ query, const float* __restrict__ ipw,
    const float* __restrict__ relw, const float* __restrict__ outw,
    bf16_t* __restrict__ qb, bf16_t* __restrict__ ipwb,
    bf16_t* __restrict__ relwb, bf16_t* __restrict__ outwb) {
  const int i = blockIdx.x * 256 + threadIdx.x;
  constexpr int N1 = ROWS_ * E_ / 4;
  constexpr int N2 = 3 * E_ * E_ / 4;
  constexpr int N3 = 512 * E_ / 4;
  constexpr int N4 = E_ * E_ / 4;
  const float4* src;
  bf16_t* dst;
  int j = i;
  if (i < N1) { src = (const float4*)query; dst = qb; }
  else if (i < N1 + N2) { src = (const float4*)ipw; dst = ipwb; j = i - N1; }
  else if (i < N1 + N2 + N3) { src = (const float4*)relw; dst = relwb; j = i - N1 - N2; }
  else if (i < N1 + N2 + N3 + N4) { src = (const float4*)outw; dst = outwb; j = i - N1 - N2 - N3; }
  else return;
  const float4 v = src[j];
  bf16x4 o;
  o[0] = (bf16_t)v.x; o[1] = (bf16_t)v.y;
  o[2] = (bf16_t)v.z; o[3] = (bf16_t)v.w;
  ((bf16x4*)dst)[j] = o;
}

// ---------------------------------------------------------------------------
// Combined projection GEMM, BM=192 x BN=256 x BK=64, 512 threads, r2
// schedule, split in two dispatches. Q is scaled by 0.125*log2(e) so the
// attention softmax can use exp2 directly (exp(x) == exp2(x*log2e)).
// ---------------------------------------------------------------------------
__device__ __forceinline__ int sw256(int row, int col) {
  // XOR-swizzled bounce layout for the 192x256 V-tile transpose
  return row * 256 + ((((col >> 3) ^ (row & 31)) << 3) | (col & 7));
}

__global__ __launch_bounds__(512, 2) void bgemm_proj(
    const bf16_t* __restrict__ A, const bf16_t* __restrict__ W,
    const float* __restrict__ ipb, const float* __restrict__ relb,
    bf16_t* __restrict__ qkvb, float* __restrict__ relv2,
    bf16_t* __restrict__ vT, int bn0) {
  // [As0|As1] 2x192x64, [Bs0|Bs1] 2x256x64  (112 KB total)
  __shared__ bf16_t smem[57344];
  bf16_t* As0 = smem;
  bf16_t* As1 = smem + 12288;
  bf16_t* Bs0 = smem + 24576;
  bf16_t* Bs1 = smem + 24576 + 16384;

  const int tid = threadIdx.x;
  const int wave = tid >> 6, lane = tid & 63;
  const int wr = wave >> 2, wc = wave & 3;       // 2 x 4 wave grid
  // bijective XCD swizzle; nwg is 256 or 192, both divisible by 8.
  const int nx = gridDim.x;
  const int pid = blockIdx.y * nx + blockIdx.x;
  const int chunk = (nx * gridDim.y) >> 3;
  const int lid = (pid & 7) * chunk + (pid >> 3);
  const int by = lid / nx;
  const int bx = lid - by * nx;
  const int bm = by * 192, bn = bn0 + bx * 256;
  const int q = lane >> 4, ln = lane & 15;
  const int grow = tid >> 3;                              // 0..63
  const int gcol = ((tid & 7) ^ (grow & 7)) * 8;          // pre-swizzled src
  const int co[2] = {((q) ^ (ln & 7)) * 8, ((4 + q) ^ (ln & 7)) * 8};

  f32x4 acc[6][4];
#pragma unroll
  for (int mi = 0; mi < 6; ++mi)
#pragma unroll
    for (int ni = 0; ni < 4; ++ni)
#pragma unroll
      for (int r = 0; r < 4; ++r) acc[mi][ni][r] = 0.f;

  // stage one K-tile (7 GLL per thread: 3 A-rounds + 4 B-rounds of 64 rows)
  auto stage = [&](int kt, bf16_t* la, bf16_t* lb) {
    const int kc = kt * 64 + gcol;
#pragma unroll
    for (int p = 0; p < 3; ++p)
      GLL(&A[(size_t)(bm + p * 64 + grow) * 1024 + kc], &la[p * 4096 + tid * 8]);
#pragma unroll
    for (int p = 0; p < 4; ++p)
      GLL(&W[(size_t)(bn + p * 64 + grow) * 1024 + kc], &lb[p * 4096 + tid * 8]);
  };

  // One K-tile, barrier-free inside: reads prefetched 1 sub-phase deep.
  auto compute_tile = [&](const bf16_t* la, const bf16_t* lb) {
    bf16x8 a0[3], a1[3], b0[4], b1[4];
#pragma unroll
    for (int ni = 0; ni < 4; ++ni)
      b0[ni] = *(const bf16x8*)&lb[(wc * 64 + ni * 16 + ln) * 64 + co[0]];
#pragma unroll
    for (int mi = 0; mi < 3; ++mi)
      a0[mi] = *(const bf16x8*)&la[(wr * 96 + mi * 16 + ln) * 64 + co[0]];
#pragma unroll
    for (int mi = 0; mi < 3; ++mi)
      a1[mi] = *(const bf16x8*)&la[(wr * 96 + (3 + mi) * 16 + ln) * 64 + co[0]];
    __builtin_amdgcn_s_setprio(1);
#pragma unroll
    for (int mi = 0; mi < 3; ++mi)
#pragma unroll
      for (int ni = 0; ni < 4; ++ni)
        acc[mi][ni] = __builtin_amdgcn_mfma_f32_16x16x32_bf16(
            a0[mi], b0[ni], acc[mi][ni], 0, 0, 0);
    __builtin_amdgcn_s_setprio(0);
#pragma unroll
    for (int ni = 0; ni < 4; ++ni)
      b1[ni] = *(const bf16x8*)&lb[(wc * 64 + ni * 16 + ln) * 64 + co[1]];
#pragma unroll
    for (int mi = 0; mi < 3; ++mi)
      a0[mi] = *(const bf16x8*)&la[(wr * 96 + mi * 16 + ln) * 64 + co[1]];
    __builtin_amdgcn_s_setprio(1);
#pragma unroll
    for (int mi = 0; mi < 3; ++mi)
#pragma unroll
      for (int ni = 0; ni < 4; ++ni)
        acc[3 + mi][ni] = __builtin_amdgcn_mfma_f32_16x16x32_bf16(
            a1[mi], b0[ni], acc[3 + mi][ni], 0, 0, 0);
    __builtin_amdgcn_s_setprio(0);
#pragma unroll
    for (int mi = 0; mi < 3; ++mi)
      a1[mi] = *(const bf16x8*)&la[(wr * 96 + (3 + mi) * 16 + ln) * 64 + co[1]];
    __builtin_amdgcn_s_setprio(1);
#pragma unroll
    for (int mi = 0; mi < 3; ++mi)
#pragma unroll
      for (int ni = 0; ni < 4; ++ni)
        acc[mi][ni] = __builtin_amdgcn_mfma_f32_16x16x32_bf16(
            a0[mi], b1[ni], acc[mi][ni], 0, 0, 0);
    __builtin_amdgcn_s_setprio(0);
    __builtin_amdgcn_s_setprio(1);
#pragma unroll
    for (int mi = 0; mi < 3; ++mi)
#pragma unroll
      for (int ni = 0; ni < 4; ++ni)
        acc[3 + mi][ni] = __builtin_amdgcn_mfma_f32_16x16x32_bf16(
            a1[mi], b1[ni], acc[3 + mi][ni], 0, 0, 0);
    __builtin_amdgcn_s_setprio(0);
  };

  // prologue: 2 K-tiles in flight (14 outstanding GLL per thread)
  stage(0, As0, Bs0);
  stage(1, As1, Bs1);

  for (int kt = 0; kt < 16; kt += 2) {
    WVM7(); BARX();                       // tile kt resident for all waves
    compute_tile(As0, Bs0);
    BARX();                               // all waves done reading buf0
    if (kt + 2 < 16) stage(kt + 2, As0, Bs0);
    if (kt < 14) { WVM7(); } else { WVM0(); }   // tile kt+1 resident
    BARX();
    compute_tile(As1, Bs1);
    BARX();                               // all waves done reading buf1
    if (kt + 3 < 16) stage(kt + 3, As1, Bs1);
  }

  // ---------------- epilogue (per-block uniform routing) -------------------
  if (bn < 2048) {
    // Q (scaled by 0.125*log2e for exp2 softmax) and K -> qkvb
    const float sc = (bn < 1024) ? 0.125f * LOG2E_ : 1.0f;
#pragma unroll
    for (int mi = 0; mi < 6; ++mi) {
#pragma unroll
      for (int ni = 0; ni < 4; ++ni) {
        const int col = bn + wc * 64 + ni * 16 + ln;
        const float bv = ipb[col];
#pragma unroll
        for (int r = 0; r < 4; ++r) {
          const int row = bm + wr * 96 + mi * 16 + q * 4 + r;
          qkvb[(size_t)row * 3072 + col] = (bf16_t)((acc[mi][ni][r] + bv) * sc);
        }
      }
    }
  } else if (bn < 3072) {
    // V: transpose in-block via swizzled LDS bounce, write vT[bh][d][token]
    __syncthreads();  // K-loop LDS fully drained; reuse smem as bounce
#pragma unroll
    for (int mi = 0; mi < 6; ++mi) {
#pragma unroll
      for (int ni = 0; ni < 4; ++ni) {
        const int col_l = wc * 64 + ni * 16 + ln;
        const float bv = ipb[bn + col_l];
#pragma unroll
        for (int r = 0; r < 4; ++r) {
          const int row_l = wr * 96 + mi * 16 + q * 4 + r;
          smem[sw256(row_l, col_l)] = (bf16_t)(acc[mi][ni][r] + bv);
        }
      }
    }
    __syncthreads();
    const int h0 = (bn - 2048) >> 6;     // 4 heads per 256-col tile
    const int tb0 = bm >> 2;             // 48 tokens per 192-row tile
#pragma unroll
    for (int e = 0; e < 2; ++e) {
      const int task = e * 512 + tid;    // 1024 tasks: (b, col)
      const int b = task & 3;
      const int c = task >> 2;           // 0..255
      const int h = h0 + (c >> 6);
      const int d = c & 63;
      const size_t base = ((size_t)((b * 16 + h) * 64 + d)) * (size_t)TGT_ + tb0;
#pragma unroll
      for (int k = 0; k < 6; ++k) {
        bf16x8 v8;
#pragma unroll
        for (int i = 0; i < 8; ++i)
          v8[i] = smem[sw256((k * 8 + i) * 4 + b, c)];
        *(bf16x8*)&vT[base + k * 8] = v8;
      }
    }
  } else {
    const int cb = bn - 3072 + wc * 64;
    float4 rb4;
#pragma unroll
    for (int ni = 0; ni < 4; ++ni)
      ((float*)&rb4)[ni] = relb[cb + ni * 16 + ln];
    const int bkbase = cb >> 4;
#pragma unroll
    for (int mi = 0; mi < 6; ++mi) {
#pragma unroll
      for (int r = 0; r < 4; ++r) {
        const int row = bm + wr * 96 + mi * 16 + q * 4 + r;
        float4 v;
        v.x = acc[mi][0][r] + rb4.x;
        v.y = acc[mi][1][r] + rb4.y;
        v.z = acc[mi][2][r] + rb4.z;
        v.w = acc[mi][3][r] + rb4.w;
        *(float4*)&relv2[(size_t)row * 512 + ln * 32 + bkbase] = v;
      }
    }
  }
}

// ---------------------------------------------------------------------------
// Output projection GEMM (fp32 out). BM=192 x BN=128, 256 threads, dbuf
// 80 KB LDS, grid 8x32 = 256 blocks = exactly 1 block/CU, single round.
// ---------------------------------------------------------------------------
__global__ __launch_bounds__(256, 1) void bgemm_out(
    const bf16_t* __restrict__ A, const bf16_t* __restrict__ W,
    const float* __restrict__ bias, float* __restrict__ C) {
  // slot s: A at s*20480 (192x64), B at s*20480+12288 (128x64); 80 KB
  __shared__ bf16_t smem[40960];

  const int tid = threadIdx.x;
  const int wave = tid >> 6, lane = tid & 63;
  const int wr = wave >> 1, wc = wave & 1;        // 2x2 wave grid
  const int pid = blockIdx.y * 8 + blockIdx.x;    // 256 = 8*32
  const int lid = (pid & 7) * 32 + (pid >> 3);
  const int bm = (lid >> 3) * 192, bn = (lid & 7) * 128;
  const int q = lane >> 4, ln = lane & 15;
  const int grow = tid >> 3;                      // 0..31
  const int gcol = ((tid & 7) ^ (grow & 7)) * 8;
  const int co[2] = {((q) ^ (ln & 7)) * 8, ((4 + q) ^ (ln & 7)) * 8};

  f32x4 acc[6][4];
#pragma unroll
  for (int mi = 0; mi < 6; ++mi)
#pragma unroll
    for (int ni = 0; ni < 4; ++ni)
#pragma unroll
      for (int r = 0; r < 4; ++r) acc[mi][ni][r] = 0.f;

  // 10 GLL per thread per tile: A 6 rounds of 32 rows, B 4 rounds.
  auto stage = [&](int kt) {
    bf16_t* s = smem + (kt & 1) * 20480;
    const int kc = kt * 64 + gcol;
#pragma unroll
    for (int p = 0; p < 6; ++p)
      GLL(&A[(size_t)(bm + p * 32 + grow) * 1024 + kc], &s[p * 2048 + tid * 8]);
#pragma unroll
    for (int p = 0; p < 4; ++p)
      GLL(&W[(size_t)(bn + p * 32 + grow) * 1024 + kc],
          &s[12288 + p * 2048 + tid * 8]);
  };

  auto compute_tile = [&](int kt) {
    const bf16_t* la = smem + (kt & 1) * 20480;
    const bf16_t* lb = la + 12288;
    bf16x8 a0[3], a1[3], b0[4], b1[4];
#pragma unroll
    for (int ni = 0; ni < 4; ++ni)
      b0[ni] = *(const bf16x8*)&lb[(wc * 64 + ni * 16 + ln) * 64 + co[0]];
#pragma unroll
    for (int mi = 0; mi < 3; ++mi)
      a0[mi] = *(const bf16x8*)&la[(wr * 96 + mi * 16 + ln) * 64 + co[0]];
#pragma unroll
    for (int mi = 0; mi < 3; ++mi)
      a1[mi] = *(const bf16x8*)&la[(wr * 96 + (3 + mi) * 16 + ln) * 64 + co[0]];
    __builtin_amdgcn_s_setprio(1);
#pragma unroll
    for (int mi = 0; mi < 3; ++mi)
#pragma unroll
      for (int ni = 0; ni < 4; ++ni)
        acc[mi][ni] = __builtin_amdgcn_mfma_f32_16x16x32_bf16(
            a0[mi], b0[ni], acc[mi][ni], 0, 0, 0);
    __builtin_amdgcn_s_setprio(0);
#pragma unroll
    for (int ni = 0; ni < 4; ++ni)
      b1[ni] = *(const bf16x8*)&lb[(wc * 64 + ni * 16 + ln) * 64 + co[1]];
#pragma unroll
    for (int mi = 0; mi < 3; ++mi)
      a0[mi] = *(const bf16x8*)&la[(wr * 96 + mi * 16 + ln) * 64 + co[1]];
    __builtin_amdgcn_s_setprio(1);
#pragma unroll
    for (int mi = 0; mi < 3; ++mi)
#pragma unroll
      for (int ni = 0; ni < 4; ++ni)
        acc[3 + mi][ni] = __builtin_amdgcn_mfma_f32_16x16x32_bf16(
            a1[mi], b0[ni], acc[3 + mi][ni], 0, 0, 0);
    __builtin_amdgcn_s_setprio(0);
#pragma unroll
    for (int mi = 0; mi < 3; ++mi)
      a1[mi] = *(const bf16x8*)&la[(wr * 96 + (3 + mi) * 16 + ln) * 64 + co[1]];
    __builtin_amdgcn_s_setprio(1);
#pragma unroll
    for (int mi = 0; mi < 3; ++mi)
#pragma unroll
      for (int ni = 0; ni < 4; ++ni)
        acc[mi][ni] = __builtin_amdgcn_mfma_f32_16x16x32_bf16(
            a0[mi], b1[ni], acc[mi][ni], 0, 0, 0);
    __builtin_amdgcn_s_setprio(0);
    __builtin_amdgcn_s_setprio(1);
#pragma unroll
    for (int mi = 0; mi < 3; ++mi)
#pragma unroll
      for (int ni = 0; ni < 4; ++ni)
        acc[3 + mi][ni] = __builtin_amdgcn_mfma_f32_16x16x32_bf16(
            a1[mi], b1[ni], acc[3 + mi][ni], 0, 0, 0);
    __builtin_amdgcn_s_setprio(0);
  };

  stage(0);
  stage(1);

  for (int kt = 0; kt < 16; kt += 2) {
    WVM10(); BARX();                      // tile kt resident
    compute_tile(kt);
    BARX();
    if (kt + 2 < 16) stage(kt + 2);
    if (kt < 14) { WVM10(); } else { WVM0(); }  // tile kt+1 resident
    BARX();
    compute_tile(kt + 1);
    BARX();
    if (kt + 3 < 16) stage(kt + 3);
  }

#pragma unroll
  for (int mi = 0; mi < 6; ++mi) {
#pragma unroll
    for (int ni = 0; ni < 4; ++ni) {
      const int col = bn + wc * 64 + ni * 16 + ln;
      const float bv = bias[col];
#pragma unroll
      for (int r = 0; r < 4; ++r) {
        const int row = bm + wr * 96 + mi * 16 + q * 4 + r;
        C[(size_t)row * 1024 + col] = acc[mi][ni][r] + bv;
      }
    }
  }
}

// ---------------------------------------------------------------------------
// MFMA flash attention. ROUND-11: revert to the proven r7 structure
// (256 threads, 64-row Q tiles, double-buffered K/V, complementary-qt
// CU pairing — 54.6us measured), keeping only the exp2 fold from r10
// (numerically verified): bias staged x log2e, Q pre-scaled in proj,
// v_exp_f32 used directly. r9/r10 occupancy attacks both failed:
// r9 spilled (launch_bounds min-waves forced 84 VGPR), r10 supplied the
// same 8 waves/CU but lost double-buffering (+2x staging volume).
// ---------------------------------------------------------------------------
__device__ __forceinline__ int bucket_of(int n) {
  if (n < 16) return n;
  const float lf = __log2f((float)n);
  int b = (int)(16.0f + (lf - 4.0f) * 5.3333333f);
  return b > 31 ? 31 : b;
}

__global__ __launch_bounds__(256, 2) void flash_mfma(
    const bf16_t* __restrict__ qkvb, const bf16_t* __restrict__ vT,
    const float* __restrict__ relv2, bf16_t* __restrict__ attn) {
  __shared__ bf16_t Ks[2][64 * 64];
  __shared__ bf16_t Vts[2][64 * 64];
  __shared__ bf16_t Ps[4][16 * 64];
  __shared__ bf16_t biasS[3][64 * 33];

  const int bh = blockIdx.x;               // fast dim: uniform per XCD
  const int yy = blockIdx.y;
  const int qt = (yy < 4) ? (7 - yy) : (yy - 4);   // complementary CU pairs
  const int tq0 = qt * 64;
  const int b = bh >> 4, h = bh & 15;
  const int tid = threadIdx.x;
  const int wave = tid >> 6, lane = tid & 63;
  const int q = lane >> 4, ln = lane & 15;
  const int m0 = wave * 16;
  const int grow = tid >> 3;
  const int gcol = ((tid & 7) ^ (grow & 7)) * 8;
  const int co[2] = {((q) ^ (ln & 7)) * 8, ((4 + q) ^ (ln & 7)) * 8};

  // stage bias tables for all 3 streams, scaled by log2e (exp2 path)
#pragma unroll
  for (int z = 0; z < 3; ++z) {
#pragma unroll
    for (int u = 0; u < 2; ++u) {
      const int c = u * 256 + tid;
      const int row = c >> 3, j4 = (c & 7) * 4;
      const float4 v = *(const float4*)
          &relv2[((size_t)(z * T_ + tq0 + row) * B_ + b) * 512 + h * 32 + j4];
      biasS[z][row * 33 + j4 + 0] = (bf16_t)(v.x * LOG2E_);
      biasS[z][row * 33 + j4 + 1] = (bf16_t)(v.y * LOG2E_);
      biasS[z][row * 33 + j4 + 2] = (bf16_t)(v.z * LOG2E_);
      biasS[z][row * 33 + j4 + 3] = (bf16_t)(v.w * LOG2E_);
    }
  }

#pragma unroll
  for (int u = 0; u < 2; ++u) {
    const int sr = u * 32 + grow;
    GLL(&qkvb[((size_t)(0 * T_ + tq0 + sr) * B_ + b) * 3072 + h * 64 + gcol],
        &Ks[0][u * 2048 + tid * 8]);
    GLL(&qkvb[((size_t)(1 * T_ + tq0 + sr) * B_ + b) * 3072 + h * 64 + gcol],
        &Vts[0][u * 2048 + tid * 8]);
    GLL(&qkvb[((size_t)(2 * T_ + tq0 + sr) * B_ + b) * 3072 + h * 64 + gcol],
        &Ks[1][u * 2048 + tid * 8]);
  }
  __syncthreads();

  bf16x8 aq[3][2];
  aq[0][0] = *(const bf16x8*)&Ks[0][(m0 + ln) * 64 + co[0]];
  aq[0][1] = *(const bf16x8*)&Ks[0][(m0 + ln) * 64 + co[1]];
  aq[1][0] = *(const bf16x8*)&Vts[0][(m0 + ln) * 64 + co[0]];
  aq[1][1] = *(const bf16x8*)&Vts[0][(m0 + ln) * 64 + co[1]];
  aq[2][0] = *(const bf16x8*)&Ks[1][(m0 + ln) * 64 + co[0]];
  aq[2][1] = *(const bf16x8*)&Ks[1][(m0 + ln) * 64 + co[1]];

  float bv31[3][4], bv0[3][4];
#pragma unroll
  for (int z = 0; z < 3; ++z)
#pragma unroll
    for (int r = 0; r < 4; ++r) {
      const int rloc = m0 + q * 4 + r;
      bv31[z][r] = (float)biasS[z][rloc * 33 + 31];
      bv0[z][r] = (float)biasS[z][rloc * 33];
    }

  f32x4 Od[3][4];
  float lpart[3][4];
#pragma unroll
  for (int z = 0; z < 3; ++z)
#pragma unroll
    for (int r = 0; r < 4; ++r) {
      lpart[z][r] = 0.f;
#pragma unroll
      for (int tc = 0; tc < 4; ++tc) Od[z][tc][r] = 0.f;
    }

  const int ntiles = qt + 3;

  auto stage_tile = [&](int jj, int buf) {
    const int krb = (jj <= qt) ? jj * 64 : ((jj - qt) * T_ + tq0);
#pragma unroll
    for (int u = 0; u < 2; ++u) {
      const int sr = u * 32 + grow;
      GLL(&qkvb[((size_t)(krb + sr) * B_ + b) * 3072 + 1024 + h * 64 + gcol],
          &Ks[buf][u * 2048 + tid * 8]);
      GLL(&vT[((size_t)bh * 64 + sr) * (size_t)TGT_ + krb + gcol],
          &Vts[buf][u * 2048 + tid * 8]);
    }
  };

  __syncthreads();
  stage_tile(0, 0);
  __syncthreads();

  for (int jj = 0; jj < ntiles; ++jj) {
    const int cur = jj & 1;
    if (jj + 1 < ntiles) stage_tile(jj + 1, cur ^ 1);

    const int krb = (jj <= qt) ? jj * 64 : ((jj - qt) * T_ + tq0);

    bf16x8 kf[4][2], vf[4][2];
#pragma unroll
    for (int tc = 0; tc < 4; ++tc) {
      kf[tc][0] = *(const bf16x8*)&Ks[cur][(tc * 16 + ln) * 64 + co[0]];
      kf[tc][1] = *(const bf16x8*)&Ks[cur][(tc * 16 + ln) * 64 + co[1]];
      vf[tc][0] = *(const bf16x8*)&Vts[cur][(tc * 16 + ln) * 64 + co[0]];
      vf[tc][1] = *(const bf16x8*)&Vts[cur][(tc * 16 + ln) * 64 + co[1]];
    }

    if (jj <= qt) {
      const bool far = (jj <= qt - 3);
      // per-z sequential: QK^T -> softmax (exp2) -> Ps -> PV
#pragma unroll
      for (int z = 0; z < 3; ++z) {
        f32x4 acc[4];
#pragma unroll
        for (int tc = 0; tc < 4; ++tc)
#pragma unroll
          for (int r = 0; r < 4; ++r) acc[tc][r] = 0.f;
#pragma unroll
        for (int tc = 0; tc < 4; ++tc) {
          acc[tc] = __builtin_amdgcn_mfma_f32_16x16x32_bf16(aq[z][0], kf[tc][0], acc[tc], 0, 0, 0);
          acc[tc] = __builtin_amdgcn_mfma_f32_16x16x32_bf16(aq[z][1], kf[tc][1], acc[tc], 0, 0, 0);
        }

        if (far) {
#pragma unroll
          for (int r = 0; r < 4; ++r) {
            const float bv = bv31[z][r];
#pragma unroll
            for (int tc = 0; tc < 4; ++tc) {
              const float p = EXP2F(acc[tc][r] + bv);
              lpart[z][r] += p;
              const int pc = (tc * 2 + (ln >> 3)) ^ ((q * 4 + r) & 7);
              Ps[wave][(q * 4 + r) * 64 + pc * 8 + (ln & 7)] = (bf16_t)p;
            }
          }
        } else {
#pragma unroll
          for (int r = 0; r < 4; ++r) {
            const int rloc = m0 + q * 4 + r;
            const int dbase = tq0 + rloc - krb;
#pragma unroll
            for (int tc = 0; tc < 4; ++tc) {
              const int sl = tc * 16 + ln;
              const int d = dbase - sl;
              const bool valid = (jj < qt) | (d >= 0);
              int n = d < 0 ? 0 : d;
              if (z > 0) n += 1;
              const float bv = (float)biasS[z][rloc * 33 + bucket_of(n)];
              const float p = valid ? EXP2F(acc[tc][r] + bv) : 0.f;
              lpart[z][r] += p;
              const int pc = (tc * 2 + (ln >> 3)) ^ ((q * 4 + r) & 7);
              Ps[wave][(q * 4 + r) * 64 + pc * 8 + (ln & 7)] = (bf16_t)p;
            }
          }
        }

        bf16x8 ap[2];
        ap[0] = *(const bf16x8*)&Ps[wave][ln * 64 + co[0]];
        ap[1] = *(const bf16x8*)&Ps[wave][ln * 64 + co[1]];
#pragma unroll
        for (int tc = 0; tc < 4; ++tc) {
          Od[z][tc] = __builtin_amdgcn_mfma_f32_16x16x32_bf16(ap[0], vf[tc][0], Od[z][tc], 0, 0, 0);
          Od[z][tc] = __builtin_amdgcn_mfma_f32_16x16x32_bf16(ap[1], vf[tc][1], Od[z][tc], 0, 0, 0);
        }
      }
    } else {
      // diagonal predict tile: only stream z == jj - qt
#pragma unroll
      for (int z = 1; z <= 2; ++z) {
        if (jj - qt == z) {
          f32x4 acc[4];
#pragma unroll
          for (int tc = 0; tc < 4; ++tc)
#pragma unroll
            for (int r = 0; r < 4; ++r) acc[tc][r] = 0.f;
#pragma unroll
          for (int tc = 0; tc < 4; ++tc) {
            acc[tc] = __builtin_amdgcn_mfma_f32_16x16x32_bf16(aq[z][0], kf[tc][0], acc[tc], 0, 0, 0);
            acc[tc] = __builtin_amdgcn_mfma_f32_16x16x32_bf16(aq[z][1], kf[tc][1], acc[tc], 0, 0, 0);
          }
#pragma unroll
          for (int r = 0; r < 4; ++r) {
            const int rloc = m0 + q * 4 + r;
            const float bv = bv0[z][r];
#pragma unroll
            for (int tc = 0; tc < 4; ++tc) {
              const int sl = tc * 16 + ln;
              const float p = (sl == rloc) ? EXP2F(acc[tc][r] + bv) : 0.f;
              lpart[z][r] += p;
              const int pc = (tc * 2 + (ln >> 3)) ^ ((q * 4 + r) & 7);
              Ps[wave][(q * 4 + r) * 64 + pc * 8 + (ln & 7)] = (bf16_t)p;
            }
          }
          bf16x8 ap[2];
          ap[0] = *(const bf16x8*)&Ps[wave][ln * 64 + co[0]];
          ap[1] = *(const bf16x8*)&Ps[wave][ln * 64 + co[1]];
#pragma unroll
          for (int tc = 0; tc < 4; ++tc) {
            Od[z][tc] = __builtin_amdgcn_mfma_f32_16x16x32_bf16(ap[0], vf[tc][0], Od[z][tc], 0, 0, 0);
            Od[z][tc] = __builtin_amdgcn_mfma_f32_16x16x32_bf16(ap[1], vf[tc][1], Od[z][tc], 0, 0, 0);
          }
        }
      }
    }
    __syncthreads();
  }

  // epilogue: reduce row sums, normalize, store
#pragma unroll
  for (int z = 0; z < 3; ++z) {
#pragma unroll
    for (int r = 0; r < 4; ++r) {
      float l = lpart[z][r];
      l += __shfl_xor(l, 1, 16);
      l += __shfl_xor(l, 2, 16);
      l += __shfl_xor(l, 4, 16);
      l += __shfl_xor(l, 8, 16);
      const float inv = 1.f / l;
      const size_t rowbase =
          ((size_t)(z * T_ + tq0 + m0 + q * 4 + r) * B_ + b) * (size_t)E_ + h * 64;
#pragma unroll
      for (int tc = 0; tc < 4; ++tc)
        attn[rowbase + tc * 16 + ln] = (bf16_t)(Od[z][tc][r] * inv);
    }
  }
}

// ---------------------------------------------------------------------------
extern "C" void kernel_launch(void* const* d_in, const int* in_sizes, int n_in,
                              void* d_out, int out_size, void* d_ws, size_t ws_size,
                              hipStream_t stream) {
  const float* query = (const float*)d_in[0];
  const float* ipw   = (const float*)d_in[1];
  const float* ipb   = (const float*)d_in[2];
  const float* relw  = (const float*)d_in[3];
  const float* relb  = (const float*)d_in[4];
  const float* outw  = (const float*)d_in[5];
  const float* outb  = (const float*)d_in[6];
  float* out = (float*)d_out;

  bf16_t* qkvb  = (bf16_t*)d_ws;                                 // 6144x3072
  float*  relv2 = (float*)(qkvb + (size_t)ROWS_ * 3 * E_);       // 6144x512 f32
  bf16_t* qb    = (bf16_t*)(relv2 + (size_t)ROWS_ * 512);        // 6144x1024
  bf16_t* ipwb  = qb + (size_t)ROWS_ * E_;                       // 3072x1024
  bf16_t* relwb = ipwb + (size_t)(3 * E_) * E_;                  // 512x1024 (adjacent!)
  bf16_t* outwb = relwb + (size_t)512 * E_;                      // 1024x1024
  bf16_t* attnb = outwb + (size_t)E_ * E_;                       // 6144x1024
  bf16_t* vT    = attnb + (size_t)ROWS_ * E_;                    // 64x64x1536

  const dim3 blk(256);

  // 1) conversions
  {
    const int ntot = (ROWS_ * E_ + 3 * E_ * E_ + 512 * E_ + E_ * E_) / 4;
    prep<<<dim3((ntot + 255) / 256), blk, 0, stream>>>(
        query, ipw, relw, outw, qb, ipwb, relwb, outwb);
  }

  // 2a) Q+K projection: 256 blocks = exactly 1 full round
  bgemm_proj<<<dim3(8, 32), dim3(512), 0, stream>>>(
      qb, ipwb, ipb, relb, qkvb, relv2, vT, 0);
  // 2b) V + rel projection: 192 blocks = 1 round at 75%
  bgemm_proj<<<dim3(6, 32), dim3(512), 0, stream>>>(
      qb, ipwb, ipb, relb, qkvb, relv2, vT, 2048);

  // 3) flash attention: r7 structure (dbuf, complementary-qt), exp2 softmax
  flash_mfma<<<dim3(64, 8), blk, 0, stream>>>(
      qkvb, vT, relv2, attnb);

  // 4) output projection: 256 blocks = exactly 1 round
  bgemm_out<<<dim3(8, 32), blk, 0, stream>>>(
      attnb, outwb, outb, out);
}